// Round 4
// baseline (5091.509 us; speedup 1.0000x reference)
//
#include <hip/hip_runtime.h>
#include <hip/hip_bf16.h>

#define HID 64
#define MSG 128
#define NDIM 32
#define EDIM 16
#define NG 512

typedef unsigned short u16;
typedef unsigned int u32;

__device__ __forceinline__ float b2f(u16 u){union{u32 i;float f;}v;v.i=((u32)u)<<16;return v.f;}
__device__ __forceinline__ u16 f2b(float f){union{float f;u32 i;}v;v.f=f;u32 r=v.i+0x7FFF+((v.i>>16)&1);return (u16)(r>>16);}
__device__ __forceinline__ u32 pack2(float a,float b){return (u32)f2b(a)|((u32)f2b(b)<<16);}
__device__ __forceinline__ float blo(u32 w){union{u32 i;float f;}v;v.i=w<<16;return v.f;}
__device__ __forceinline__ float bhi(u32 w){union{u32 i;float f;}v;v.i=w&0xffff0000u;return v.f;}
__device__ __forceinline__ float sigm(float x){return 1.0f/(1.0f+expf(-x));}
__device__ __forceinline__ int rfl(int x){return __builtin_amdgcn_readfirstlane(x);}

// ---------------- CSR build ----------------
__global__ void k_hist(const int* __restrict__ idx, int n, int* __restrict__ cnt) {
    int i = blockIdx.x * blockDim.x + threadIdx.x;
    int stride = gridDim.x * blockDim.x;
    for (; i < n; i += stride) atomicAdd(&cnt[idx[i]], 1);
}

// single-block chunked exclusive scan, out[n] = total. block = 1024.
__global__ void k_scan(const int* __restrict__ in, int* __restrict__ out, int n) {
    __shared__ int sums[1024];
    int tid = threadIdx.x;
    int chunk = (n + 1023) >> 10;
    int begin = tid * chunk;
    int endp = begin + chunk; if (endp > n) endp = n;
    int s = 0;
    for (int i = begin; i < endp; i++) s += in[i];
    sums[tid] = s;
    __syncthreads();
    for (int off = 1; off < 1024; off <<= 1) {
        int t = (tid >= off) ? sums[tid - off] : 0;
        __syncthreads();
        sums[tid] += t;
        __syncthreads();
    }
    int run = sums[tid] - s;
    for (int i = begin; i < endp; i++) { out[i] = run; run += in[i]; }
    if (tid == 1023) out[n] = sums[1023];
}

__global__ void k_gptr(const int* __restrict__ batch, int N, int* __restrict__ gptr) {
    int g = blockIdx.x * blockDim.x + threadIdx.x;
    if (g > NG) return;
    int lo = 0, hi = N;
    while (lo < hi) { int mid = (lo + hi) >> 1; if (batch[mid] < g) lo = mid + 1; else hi = mid; }
    gptr[g] = lo;
}

__global__ void k_scatter(const int* __restrict__ src, const int* __restrict__ dst, int n,
                          const int* __restrict__ ptr, int* __restrict__ cursor,
                          int2* __restrict__ esl) {
    int i = blockIdx.x * blockDim.x + threadIdx.x;
    int stride = gridDim.x * blockDim.x;
    for (; i < n; i += stride) {
        int d = dst[i];
        int pos = ptr[d] + atomicAdd(&cursor[d], 1);
        esl[pos] = make_int2(i, src[i]);
    }
}

// ---------------- node embedding ----------------
__global__ void k_embed(const float* __restrict__ xf, const float* __restrict__ We,
                        const float* __restrict__ be, float* __restrict__ xh, int N) {
    __shared__ float Wl[NDIM * HID];
    for (int t = threadIdx.x; t < NDIM * HID; t += blockDim.x) Wl[t] = We[t];
    __syncthreads();
    int total = N * HID;
    int stride = gridDim.x * blockDim.x;
    for (int idx = blockIdx.x * blockDim.x + threadIdx.x; idx < total; idx += stride) {
        int n = idx >> 6, c = idx & 63;
        const float* xr = xf + n * NDIM;
        float acc = be[c];
#pragma unroll
        for (int k = 0; k < NDIM; k++) acc += xr[k] * Wl[k * HID + c];
        xh[idx] = acc;
    }
}

// ---------------- k_prep: Pd (-> Hb) and Ps; wave = 256 out-ch (float4/lane), T=8 nodes ----------------
__global__ void __launch_bounds__(256)
k_prep(const float* __restrict__ xh, const float* __restrict__ Wm1,
       const float* __restrict__ bm1, float* __restrict__ Hb,
       float* __restrict__ Ps, int N) {
    __shared__ float Wl[64 * 256];
    for (int t = threadIdx.x; t < 64 * 256; t += 256) {
        int k = t >> 8, cc = t & 255;
        Wl[t] = (cc < 128) ? Wm1[k * 128 + cc] : Wm1[(64 + k) * 128 + (cc - 128)];
    }
    __syncthreads();
    int wv = threadIdx.x >> 6, lane = threadIdx.x & 63;
    int cc = lane * 4;
    float4 bias;
    if (lane < 32) bias = *(const float4*)&bm1[cc];
    else bias = make_float4(0.f, 0.f, 0.f, 0.f);
    int ngroups = (N + 7) >> 3;
    for (int g = blockIdx.x * 4 + wv; g < ngroups; g += gridDim.x * 4) {
        int base = rfl(g) * 8;
        const float* xp[8];
#pragma unroll
        for (int t = 0; t < 8; t++) {
            int d = base + t; if (d > N - 1) d = N - 1;
            xp[t] = xh + (size_t)d * 64;
        }
        float4 acc[8];
#pragma unroll
        for (int t = 0; t < 8; t++) acc[t] = bias;
        for (int k = 0; k < 64; k += 4) {
            float4 xv4[8];
#pragma unroll
            for (int t = 0; t < 8; t++) xv4[t] = *(const float4*)&xp[t][k];
#pragma unroll
            for (int kk = 0; kk < 4; kk++) {
                float4 w = *(const float4*)&Wl[(k + kk) * 256 + cc];
#pragma unroll
                for (int t = 0; t < 8; t++) {
                    float xv = kk == 0 ? xv4[t].x : kk == 1 ? xv4[t].y : kk == 2 ? xv4[t].z : xv4[t].w;
                    acc[t].x += xv * w.x; acc[t].y += xv * w.y;
                    acc[t].z += xv * w.z; acc[t].w += xv * w.w;
                }
            }
        }
#pragma unroll
        for (int t = 0; t < 8; t++) {
            int d = base + t;
            if (d < N) {
                if (lane < 32) *(float4*)&Hb[(size_t)d * 128 + cc] = acc[t];
                else *(float4*)&Ps[(size_t)d * 128 + (cc - 128)] = acc[t];
            }
        }
    }
}

// ---------------- k_edge: H[d] = sum_e relu(Pd[d] + Ps[src] + W1e@ea) — no LDS, no shfl ----------------
__device__ __forceinline__ float edot16(const float* __restrict__ e, const float* w) {
    float4 a = *(const float4*)e;
    float4 b = *(const float4*)(e + 4);
    float4 c4 = *(const float4*)(e + 8);
    float4 d4 = *(const float4*)(e + 12);
    return a.x*w[0] + a.y*w[1] + a.z*w[2] + a.w*w[3]
         + b.x*w[4] + b.y*w[5] + b.z*w[6] + b.w*w[7]
         + c4.x*w[8] + c4.y*w[9] + c4.z*w[10] + c4.w*w[11]
         + d4.x*w[12] + d4.y*w[13] + d4.z*w[14] + d4.w*w[15];
}

__global__ void __launch_bounds__(256)
k_edge(const float* __restrict__ Ps, const float* __restrict__ ea,
       const float* __restrict__ Wm1, const int* __restrict__ ptr,
       const int2* __restrict__ esl, float* __restrict__ Hb, int N) {
    int c = threadIdx.x & 127;
    int half = threadIdx.x >> 7;
    float w[16];
#pragma unroll
    for (int k = 0; k < 16; k++) w[k] = Wm1[128 * 128 + k * 128 + c];
    for (int dd = blockIdx.x * 2 + half; dd < N; dd += gridDim.x * 2) {
        int d = rfl(dd);
        float pd = Hb[(size_t)d * 128 + c];
        int eb = ptr[d], ee = ptr[d + 1];
        float acc = 0.f;
        int i = eb;
        for (; i + 4 <= ee; i += 4) {
            int2 q0 = esl[i], q1 = esl[i + 1], q2 = esl[i + 2], q3 = esl[i + 3];
            int e0 = rfl(q0.x), n0 = rfl(q0.y);
            int e1 = rfl(q1.x), n1 = rfl(q1.y);
            int e2 = rfl(q2.x), n2 = rfl(q2.y);
            int e3 = rfl(q3.x), n3 = rfl(q3.y);
            float pv0 = Ps[(size_t)n0 * 128 + c];
            float pv1 = Ps[(size_t)n1 * 128 + c];
            float pv2 = Ps[(size_t)n2 * 128 + c];
            float pv3 = Ps[(size_t)n3 * 128 + c];
            float pe0 = edot16(ea + (size_t)e0 * EDIM, w);
            float pe1 = edot16(ea + (size_t)e1 * EDIM, w);
            float pe2 = edot16(ea + (size_t)e2 * EDIM, w);
            float pe3 = edot16(ea + (size_t)e3 * EDIM, w);
            acc += fmaxf(pd + pv0 + pe0, 0.f) + fmaxf(pd + pv1 + pe1, 0.f)
                 + fmaxf(pd + pv2 + pe2, 0.f) + fmaxf(pd + pv3 + pe3, 0.f);
        }
        for (; i < ee; i++) {
            int2 q = esl[i];
            int e0 = rfl(q.x), n0 = rfl(q.y);
            float pv = Ps[(size_t)n0 * 128 + c];
            float pe = edot16(ea + (size_t)e0 * EDIM, w);
            acc += fmaxf(pd + pv + pe, 0.f);
        }
        Hb[(size_t)d * 128 + c] = acc;
    }
}

// ---------------- m = H @ W_m2 + deg*b_m2, wave = 64 ch, T=4 nodes ----------------
__global__ void __launch_bounds__(256)
k_msg(const float* __restrict__ H, const float* __restrict__ Wm2,
      const float* __restrict__ bm2, const int* __restrict__ ptr,
      float* __restrict__ m, int N) {
    __shared__ float W2[128 * 64];
    for (int t = threadIdx.x; t < 128 * 64; t += 256) W2[t] = Wm2[t];
    __syncthreads();
    int wv = threadIdx.x >> 6, lane = threadIdx.x & 63;
    float b2 = bm2[lane];
    int ngroups = (N + 3) >> 2;
    for (int g = blockIdx.x * 4 + wv; g < ngroups; g += gridDim.x * 4) {
        int base = rfl(g) * 4;
        const float* hp[4];
#pragma unroll
        for (int t = 0; t < 4; t++) { int d = base + t; if (d > N - 1) d = N - 1; hp[t] = H + (size_t)d * 128; }
        float acc[4] = {0.f, 0.f, 0.f, 0.f};
        for (int k = 0; k < 128; k += 4) {
            float4 h4[4];
#pragma unroll
            for (int t = 0; t < 4; t++) h4[t] = *(const float4*)&hp[t][k];
#pragma unroll
            for (int kk = 0; kk < 4; kk++) {
                float w = W2[(k + kk) * 64 + lane];
#pragma unroll
                for (int t = 0; t < 4; t++) {
                    float hv = kk == 0 ? h4[t].x : kk == 1 ? h4[t].y : kk == 2 ? h4[t].z : h4[t].w;
                    acc[t] += hv * w;
                }
            }
        }
#pragma unroll
        for (int t = 0; t < 4; t++) {
            int d = base + t;
            if (d < N) {
                float deg = (float)(ptr[d + 1] - ptr[d]);
                m[(size_t)d * 64 + lane] = acc[t] + deg * b2;
            }
        }
    }
}

// ---------------- GRU cell, wave = 64 ch, T=4 nodes, packed bf16 weights in LDS ----------------
__global__ void __launch_bounds__(256)
k_gru(const float* __restrict__ m, const float* __restrict__ Wih,
      const float* __restrict__ Whh, const float* __restrict__ bih,
      const float* __restrict__ bhh, float* __restrict__ xh, int N) {
    __shared__ uint2 Wa[64 * 64];  // {Wr|Wz, Wn|Ur}
    __shared__ u32 Wb[64 * 64];    // {Uz|Un}
    for (int t = threadIdx.x; t < 64 * 64; t += 256) {
        int k = t >> 6, c = t & 63;
        Wa[t] = make_uint2(pack2(Wih[c * 64 + k], Wih[(64 + c) * 64 + k]),
                           pack2(Wih[(128 + c) * 64 + k], Whh[c * 64 + k]));
        Wb[t] = pack2(Whh[(64 + c) * 64 + k], Whh[(128 + c) * 64 + k]);
    }
    __syncthreads();
    int wv = threadIdx.x >> 6, lane = threadIdx.x & 63;
    float br = bih[lane], bz = bih[64 + lane], bn = bih[128 + lane];
    float cr = bhh[lane], cz = bhh[64 + lane], cn = bhh[128 + lane];
    int ngroups = (N + 3) >> 2;
    for (int g = blockIdx.x * 4 + wv; g < ngroups; g += gridDim.x * 4) {
        int base = rfl(g) * 4;
        const float* mp[4]; const float* hp[4];
#pragma unroll
        for (int t = 0; t < 4; t++) {
            int d = base + t; if (d > N - 1) d = N - 1;
            mp[t] = m + (size_t)d * 64; hp[t] = xh + (size_t)d * 64;
        }
        float gir[4], giz[4], gin[4], ghr[4], ghz[4], ghn[4];
#pragma unroll
        for (int t = 0; t < 4; t++) { gir[t] = br; giz[t] = bz; gin[t] = bn; ghr[t] = cr; ghz[t] = cz; ghn[t] = cn; }
        for (int k = 0; k < 64; k += 4) {
            float4 m4[4], h4[4];
#pragma unroll
            for (int t = 0; t < 4; t++) { m4[t] = *(const float4*)&mp[t][k]; h4[t] = *(const float4*)&hp[t][k]; }
#pragma unroll
            for (int kk = 0; kk < 4; kk++) {
                uint2 wa = Wa[(k + kk) * 64 + lane];
                u32 wb = Wb[(k + kk) * 64 + lane];
                float wr = blo(wa.x), wz = bhi(wa.x), wn = blo(wa.y);
                float ur = bhi(wa.y), uz = blo(wb), un = bhi(wb);
#pragma unroll
                for (int t = 0; t < 4; t++) {
                    float mk = kk == 0 ? m4[t].x : kk == 1 ? m4[t].y : kk == 2 ? m4[t].z : m4[t].w;
                    float hk = kk == 0 ? h4[t].x : kk == 1 ? h4[t].y : kk == 2 ? h4[t].z : h4[t].w;
                    gir[t] += mk * wr; giz[t] += mk * wz; gin[t] += mk * wn;
                    ghr[t] += hk * ur; ghz[t] += hk * uz; ghn[t] += hk * un;
                }
            }
        }
#pragma unroll
        for (int t = 0; t < 4; t++) {
            int d = base + t;
            if (d < N) {
                float hv = xh[(size_t)d * 64 + lane];
                float r = sigm(gir[t] + ghr[t]);
                float z = sigm(giz[t] + ghz[t]);
                float nn = tanhf(gin[t] + r * ghn[t]);
                xh[(size_t)d * 64 + lane] = (1.f - z) * nn + z * hv;
            }
        }
    }
}

// ---------------- fused Set2Set step, block = 1024 ----------------
__global__ void __launch_bounds__(1024)
k_s2s(const float* __restrict__ xh, const int* __restrict__ gptr,
      float* __restrict__ qstar, float* __restrict__ qh, float* __restrict__ qc,
      const float* __restrict__ lWih, const float* __restrict__ lWhh,
      const float* __restrict__ lbih, const float* __restrict__ lbhh,
      const float* __restrict__ Wr1, const float* __restrict__ br1,
      const float* __restrict__ Wr2, const float* __restrict__ br2,
      float* __restrict__ out, int last) {
    int b = blockIdx.x, tid = threadIdx.x;
    __shared__ float qs[128], qhl[64], g[256], red[16], asums[16], rvs[1024];
    if (tid < 128) qs[tid] = qstar[b * 128 + tid];
    else if (tid < 192) qhl[tid - 128] = qh[b * 64 + tid - 128];
    __syncthreads();
    if (tid < 256) {
        float acc = lbih[tid] + lbhh[tid];
        const float* wr = lWih + tid * 128;
#pragma unroll 8
        for (int k = 0; k < 128; k++) acc += qs[k] * wr[k];
        const float* ur = lWhh + tid * 64;
#pragma unroll 8
        for (int k = 0; k < 64; k++) acc += qhl[k] * ur[k];
        g[tid] = acc;
    }
    __syncthreads();
    if (tid < 64) {
        float ig = sigm(g[tid]), fg = sigm(g[64 + tid]);
        float gg = tanhf(g[128 + tid]), og = sigm(g[192 + tid]);
        float c = fg * qc[b * 64 + tid] + ig * gg;
        float h = og * tanhf(c);
        qc[b * 64 + tid] = c;
        qh[b * 64 + tid] = h;
        qstar[b * 128 + tid] = h;
        qhl[tid] = h;
        qs[tid] = h;
    }
    __syncthreads();
    int grp = tid >> 6, lane = tid & 63;
    int start = gptr[b], end = gptr[b + 1];
    float qv = qhl[lane];
    float mloc = -3.4e38f;
    for (int n = start + grp; n < end; n += 16) {
        float p = xh[(size_t)n * 64 + lane] * qv;
#pragma unroll
        for (int off = 32; off > 0; off >>= 1) p += __shfl_xor(p, off);
        mloc = fmaxf(mloc, p);
    }
    if (lane == 0) red[grp] = mloc;
    __syncthreads();
    float emax = red[0];
#pragma unroll
    for (int j = 1; j < 16; j++) emax = fmaxf(emax, red[j]);
    float asl = 0.f, rv = 0.f;
    for (int n = start + grp; n < end; n += 16) {
        float xv = xh[(size_t)n * 64 + lane];
        float p = xv * qv;
#pragma unroll
        for (int off = 32; off > 0; off >>= 1) p += __shfl_xor(p, off);
        float a = expf(p - emax);
        asl += a;
        rv += a * xv;
    }
    if (lane == 0) asums[grp] = asl;
    rvs[tid] = rv;
    __syncthreads();
    if (tid < 64) {
        float rt = 0.f, at = 0.f;
#pragma unroll
        for (int j = 0; j < 16; j++) { rt += rvs[tid + 64 * j]; at += asums[j]; }
        float rvec = (at > 0.f) ? rt / at : 0.f;
        qstar[b * 128 + 64 + tid] = rvec;
        qs[64 + tid] = rvec;
    }
    if (last) {
        __syncthreads();
        if (tid < 64) {
            float a2 = br1[tid];
#pragma unroll 8
            for (int k = 0; k < 128; k++) a2 += qs[k] * Wr1[k * 64 + tid];
            a2 = fmaxf(a2, 0.f);
            float v = a2 * Wr2[tid];
#pragma unroll
            for (int off = 32; off > 0; off >>= 1) v += __shfl_xor(v, off);
            if (tid == 0) out[b] = v + br2[0];
        }
    }
}

extern "C" void kernel_launch(void* const* d_in, const int* in_sizes, int n_in,
                              void* d_out, int out_size, void* d_ws, size_t ws_size,
                              hipStream_t stream) {
    const float* x_feat = (const float*)d_in[0];
    const int*   ei     = (const int*)d_in[1];
    const float* eattr  = (const float*)d_in[2];
    const int*   batch  = (const int*)d_in[3];
    const float* W_emb  = (const float*)d_in[4];
    const float* b_emb  = (const float*)d_in[5];
    const float* W_m1   = (const float*)d_in[6];
    const float* b_m1   = (const float*)d_in[7];
    const float* W_m2   = (const float*)d_in[8];
    const float* b_m2   = (const float*)d_in[9];
    const float* gWih   = (const float*)d_in[10];
    const float* gWhh   = (const float*)d_in[11];
    const float* gbih   = (const float*)d_in[12];
    const float* gbhh   = (const float*)d_in[13];
    const float* lWih   = (const float*)d_in[14];
    const float* lWhh   = (const float*)d_in[15];
    const float* lbih   = (const float*)d_in[16];
    const float* lbhh   = (const float*)d_in[17];
    const float* Wr1    = (const float*)d_in[18];
    const float* br1    = (const float*)d_in[19];
    const float* Wr2    = (const float*)d_in[20];
    const float* br2    = (const float*)d_in[21];

    int N = in_sizes[0] / NDIM;   // 50000
    int E = in_sizes[1] / 2;      // 800000

    char* w = (char*)d_ws;
    auto alloc = [&](size_t b) { char* p = w; w += (b + 511) & ~(size_t)511; return p; };
    float* xh    = (float*)alloc((size_t)N * 64 * 4);
    float* Ps    = (float*)alloc((size_t)N * 128 * 4);
    float* Hb    = (float*)alloc((size_t)N * 128 * 4);
    float* mb    = (float*)alloc((size_t)N * 64 * 4);
    int*   ptr   = (int*)alloc((size_t)(N + 1) * 4);
    int2*  esl   = (int2*)alloc((size_t)E * 8);
    char* z0 = w;
    int*   cnt    = (int*)alloc((size_t)N * 4);
    int*   cursor = (int*)alloc((size_t)N * 4);
    char* z0e = w;
    int*   gptr  = (int*)alloc((size_t)(NG + 1) * 4);
    char* z1 = w;
    float* qh    = (float*)alloc((size_t)NG * 64 * 4);
    float* qc    = (float*)alloc((size_t)NG * 64 * 4);
    float* qstar = (float*)alloc((size_t)NG * 128 * 4);
    char* z1e = w;

    hipMemsetAsync(z0, 0, (size_t)(z0e - z0), stream);
    hipMemsetAsync(z1, 0, (size_t)(z1e - z1), stream);

    k_hist<<<1024, 256, 0, stream>>>(ei + E, E, cnt);
    k_scan<<<1, 1024, 0, stream>>>(cnt, ptr, N);
    k_gptr<<<3, 256, 0, stream>>>(batch, N, gptr);
    k_scatter<<<3125, 256, 0, stream>>>(ei, ei + E, E, ptr, cursor, esl);

    k_embed<<<2048, 256, 0, stream>>>(x_feat, W_emb, b_emb, xh, N);

    int gprep = ((N + 7) / 8 + 3) / 4;
    int gnode = ((N + 3) / 4 + 3) / 4;
    for (int r = 0; r < 3; r++) {
        k_prep<<<gprep, 256, 0, stream>>>(xh, W_m1, b_m1, Hb, Ps, N);
        k_edge<<<4096, 256, 0, stream>>>(Ps, eattr, W_m1, ptr, esl, Hb, N);
        k_msg<<<gnode, 256, 0, stream>>>(Hb, W_m2, b_m2, ptr, mb, N);
        k_gru<<<gnode, 256, 0, stream>>>(mb, gWih, gWhh, gbih, gbhh, xh, N);
    }
    for (int s = 0; s < 6; s++) {
        k_s2s<<<NG, 1024, 0, stream>>>(xh, gptr, qstar, qh, qc,
                                       lWih, lWhh, lbih, lbhh,
                                       Wr1, br1, Wr2, br2, (float*)d_out, s == 5);
    }
}

// Round 5
// 1429.457 us; speedup vs baseline: 3.5618x; 3.5618x over previous
//
#include <hip/hip_runtime.h>
#include <hip/hip_bf16.h>

#define HID 64
#define MSG 128
#define NDIM 32
#define EDIM 16
#define NG 512

typedef unsigned short u16;
typedef unsigned int u32;

__device__ __forceinline__ float b2f(u16 u){union{u32 i;float f;}v;v.i=((u32)u)<<16;return v.f;}
__device__ __forceinline__ u16 f2b(float f){union{float f;u32 i;}v;v.f=f;u32 r=v.i+0x7FFF+((v.i>>16)&1);return (u16)(r>>16);}
__device__ __forceinline__ u32 pack2(float a,float b){return (u32)f2b(a)|((u32)f2b(b)<<16);}
__device__ __forceinline__ float blo(u32 w){union{u32 i;float f;}v;v.i=w<<16;return v.f;}
__device__ __forceinline__ float bhi(u32 w){union{u32 i;float f;}v;v.i=w&0xffff0000u;return v.f;}
__device__ __forceinline__ float sigm(float x){return 1.0f/(1.0f+expf(-x));}
__device__ __forceinline__ int rfl(int x){return __builtin_amdgcn_readfirstlane(x);}

// ---------------- CSR build ----------------
__global__ void k_hist(const int* __restrict__ idx, int n, int* __restrict__ cnt) {
    int i = blockIdx.x * blockDim.x + threadIdx.x;
    int stride = gridDim.x * blockDim.x;
    for (; i < n; i += stride) atomicAdd(&cnt[idx[i]], 1);
}

// single-block chunked exclusive scan, out[n] = total. block = 1024.
__global__ void k_scan(const int* __restrict__ in, int* __restrict__ out, int n) {
    __shared__ int sums[1024];
    int tid = threadIdx.x;
    int chunk = (n + 1023) >> 10;
    int begin = tid * chunk;
    int endp = begin + chunk; if (endp > n) endp = n;
    int s = 0;
    for (int i = begin; i < endp; i++) s += in[i];
    sums[tid] = s;
    __syncthreads();
    for (int off = 1; off < 1024; off <<= 1) {
        int t = (tid >= off) ? sums[tid - off] : 0;
        __syncthreads();
        sums[tid] += t;
        __syncthreads();
    }
    int run = sums[tid] - s;
    for (int i = begin; i < endp; i++) { out[i] = run; run += in[i]; }
    if (tid == 1023) out[n] = sums[1023];
}

__global__ void k_gptr(const int* __restrict__ batch, int N, int* __restrict__ gptr) {
    int g = blockIdx.x * blockDim.x + threadIdx.x;
    if (g > NG) return;
    int lo = 0, hi = N;
    while (lo < hi) { int mid = (lo + hi) >> 1; if (batch[mid] < g) lo = mid + 1; else hi = mid; }
    gptr[g] = lo;
}

__global__ void k_scatter(const int* __restrict__ src, const int* __restrict__ dst, int n,
                          const int* __restrict__ ptr, int* __restrict__ cursor,
                          int2* __restrict__ esl) {
    int i = blockIdx.x * blockDim.x + threadIdx.x;
    int stride = gridDim.x * blockDim.x;
    for (; i < n; i += stride) {
        int d = dst[i];
        int pos = ptr[d] + atomicAdd(&cursor[d], 1);
        esl[pos] = make_int2(i, src[i]);
    }
}

// ---------------- node embedding ----------------
__global__ void k_embed(const float* __restrict__ xf, const float* __restrict__ We,
                        const float* __restrict__ be, float* __restrict__ xh, int N) {
    __shared__ float Wl[NDIM * HID];
    for (int t = threadIdx.x; t < NDIM * HID; t += blockDim.x) Wl[t] = We[t];
    __syncthreads();
    int total = N * HID;
    int stride = gridDim.x * blockDim.x;
    for (int idx = blockIdx.x * blockDim.x + threadIdx.x; idx < total; idx += stride) {
        int n = idx >> 6, c = idx & 63;
        const float* xr = xf + n * NDIM;
        float acc = be[c];
#pragma unroll
        for (int k = 0; k < NDIM; k++) acc += xr[k] * Wl[k * HID + c];
        xh[idx] = acc;
    }
}

// ---------------- k_prep: Pd (-> Hb) and Ps; wave = 256 out-ch (float4/lane), T=8 nodes ----------------
__global__ void __launch_bounds__(256)
k_prep(const float* __restrict__ xh, const float* __restrict__ Wm1,
       const float* __restrict__ bm1, float* __restrict__ Hb,
       float* __restrict__ Ps, int N) {
    __shared__ float Wl[64 * 256];
    for (int t = threadIdx.x; t < 64 * 256; t += 256) {
        int k = t >> 8, cc = t & 255;
        Wl[t] = (cc < 128) ? Wm1[k * 128 + cc] : Wm1[(64 + k) * 128 + (cc - 128)];
    }
    __syncthreads();
    int wv = threadIdx.x >> 6, lane = threadIdx.x & 63;
    int cc = lane * 4;
    float4 bias;
    if (lane < 32) bias = *(const float4*)&bm1[cc];
    else bias = make_float4(0.f, 0.f, 0.f, 0.f);
    int ngroups = (N + 7) >> 3;
    for (int g = blockIdx.x * 4 + wv; g < ngroups; g += gridDim.x * 4) {
        int base = rfl(g) * 8;
        const float* xp[8];
#pragma unroll
        for (int t = 0; t < 8; t++) {
            int d = base + t; if (d > N - 1) d = N - 1;
            xp[t] = xh + (size_t)d * 64;
        }
        float4 acc[8];
#pragma unroll
        for (int t = 0; t < 8; t++) acc[t] = bias;
#pragma unroll 2
        for (int k4 = 0; k4 < 16; k4++) {
            int k = k4 * 4;
            float4 xv4[8];
#pragma unroll
            for (int t = 0; t < 8; t++) xv4[t] = *(const float4*)&xp[t][k];
#pragma unroll
            for (int kk = 0; kk < 4; kk++) {
                float4 w = *(const float4*)&Wl[(k + kk) * 256 + cc];
#pragma unroll
                for (int t = 0; t < 8; t++) {
                    float xv = kk == 0 ? xv4[t].x : kk == 1 ? xv4[t].y : kk == 2 ? xv4[t].z : xv4[t].w;
                    acc[t].x += xv * w.x; acc[t].y += xv * w.y;
                    acc[t].z += xv * w.z; acc[t].w += xv * w.w;
                }
            }
        }
#pragma unroll
        for (int t = 0; t < 8; t++) {
            int d = base + t;
            if (d < N) {
                if (lane < 32) *(float4*)&Hb[(size_t)d * 128 + cc] = acc[t];
                else *(float4*)&Ps[(size_t)d * 128 + (cc - 128)] = acc[t];
            }
        }
    }
}

// ---------------- k_edge: H[d] = sum_e relu(Pd[d] + Ps[src] + W1e@ea) — no LDS, no shfl ----------------
__device__ __forceinline__ float edot16(const float* __restrict__ e, const float* w) {
    float4 a = *(const float4*)e;
    float4 b = *(const float4*)(e + 4);
    float4 c4 = *(const float4*)(e + 8);
    float4 d4 = *(const float4*)(e + 12);
    return a.x*w[0] + a.y*w[1] + a.z*w[2] + a.w*w[3]
         + b.x*w[4] + b.y*w[5] + b.z*w[6] + b.w*w[7]
         + c4.x*w[8] + c4.y*w[9] + c4.z*w[10] + c4.w*w[11]
         + d4.x*w[12] + d4.y*w[13] + d4.z*w[14] + d4.w*w[15];
}

__global__ void __launch_bounds__(256)
k_edge(const float* __restrict__ Ps, const float* __restrict__ ea,
       const float* __restrict__ Wm1, const int* __restrict__ ptr,
       const int2* __restrict__ esl, float* __restrict__ Hb, int N) {
    int c = threadIdx.x & 127;
    int half = threadIdx.x >> 7;
    float w[16];
#pragma unroll
    for (int k = 0; k < 16; k++) w[k] = Wm1[128 * 128 + k * 128 + c];
    for (int dd = blockIdx.x * 2 + half; dd < N; dd += gridDim.x * 2) {
        int d = rfl(dd);
        float pd = Hb[(size_t)d * 128 + c];
        int eb = ptr[d], ee = ptr[d + 1];
        float acc = 0.f;
        int i = eb;
        for (; i + 4 <= ee; i += 4) {
            int2 q0 = esl[i], q1 = esl[i + 1], q2 = esl[i + 2], q3 = esl[i + 3];
            int e0 = rfl(q0.x), n0 = rfl(q0.y);
            int e1 = rfl(q1.x), n1 = rfl(q1.y);
            int e2 = rfl(q2.x), n2 = rfl(q2.y);
            int e3 = rfl(q3.x), n3 = rfl(q3.y);
            float pv0 = Ps[(size_t)n0 * 128 + c];
            float pv1 = Ps[(size_t)n1 * 128 + c];
            float pv2 = Ps[(size_t)n2 * 128 + c];
            float pv3 = Ps[(size_t)n3 * 128 + c];
            float pe0 = edot16(ea + (size_t)e0 * EDIM, w);
            float pe1 = edot16(ea + (size_t)e1 * EDIM, w);
            float pe2 = edot16(ea + (size_t)e2 * EDIM, w);
            float pe3 = edot16(ea + (size_t)e3 * EDIM, w);
            acc += fmaxf(pd + pv0 + pe0, 0.f) + fmaxf(pd + pv1 + pe1, 0.f)
                 + fmaxf(pd + pv2 + pe2, 0.f) + fmaxf(pd + pv3 + pe3, 0.f);
        }
        for (; i < ee; i++) {
            int2 q = esl[i];
            int e0 = rfl(q.x), n0 = rfl(q.y);
            float pv = Ps[(size_t)n0 * 128 + c];
            float pe = edot16(ea + (size_t)e0 * EDIM, w);
            acc += fmaxf(pd + pv + pe, 0.f);
        }
        Hb[(size_t)d * 128 + c] = acc;
    }
}

// ---------------- m = H @ W_m2 + deg*b_m2, wave = 64 ch, T=4 nodes ----------------
__global__ void __launch_bounds__(256)
k_msg(const float* __restrict__ H, const float* __restrict__ Wm2,
      const float* __restrict__ bm2, const int* __restrict__ ptr,
      float* __restrict__ m, int N) {
    __shared__ float W2[128 * 64];
    for (int t = threadIdx.x; t < 128 * 64; t += 256) W2[t] = Wm2[t];
    __syncthreads();
    int wv = threadIdx.x >> 6, lane = threadIdx.x & 63;
    float b2 = bm2[lane];
    int ngroups = (N + 3) >> 2;
    for (int g = blockIdx.x * 4 + wv; g < ngroups; g += gridDim.x * 4) {
        int base = rfl(g) * 4;
        const float* hp[4];
#pragma unroll
        for (int t = 0; t < 4; t++) { int d = base + t; if (d > N - 1) d = N - 1; hp[t] = H + (size_t)d * 128; }
        float acc[4] = {0.f, 0.f, 0.f, 0.f};
#pragma unroll 2
        for (int k4 = 0; k4 < 32; k4++) {
            int k = k4 * 4;
            float4 h4[4];
#pragma unroll
            for (int t = 0; t < 4; t++) h4[t] = *(const float4*)&hp[t][k];
#pragma unroll
            for (int kk = 0; kk < 4; kk++) {
                float w = W2[(k + kk) * 64 + lane];
#pragma unroll
                for (int t = 0; t < 4; t++) {
                    float hv = kk == 0 ? h4[t].x : kk == 1 ? h4[t].y : kk == 2 ? h4[t].z : h4[t].w;
                    acc[t] += hv * w;
                }
            }
        }
#pragma unroll
        for (int t = 0; t < 4; t++) {
            int d = base + t;
            if (d < N) {
                float deg = (float)(ptr[d + 1] - ptr[d]);
                m[(size_t)d * 64 + lane] = acc[t] + deg * b2;
            }
        }
    }
}

// ---------------- GRU cell: wave-per-node (T=1), packed bf16 weights in 48KB LDS ----------------
__global__ void __launch_bounds__(256)
k_gru(const float* __restrict__ m, const float* __restrict__ Wih,
      const float* __restrict__ Whh, const float* __restrict__ bih,
      const float* __restrict__ bhh, float* __restrict__ xh, int N) {
    __shared__ uint2 Wa[64 * 64];  // {Wr|Wz, Wn|Ur}
    __shared__ u32 Wb[64 * 64];    // {Uz|Un}
    for (int t = threadIdx.x; t < 64 * 64; t += 256) {
        int k = t >> 6, c = t & 63;
        Wa[t] = make_uint2(pack2(Wih[c * 64 + k], Wih[(64 + c) * 64 + k]),
                           pack2(Wih[(128 + c) * 64 + k], Whh[c * 64 + k]));
        Wb[t] = pack2(Whh[(64 + c) * 64 + k], Whh[(128 + c) * 64 + k]);
    }
    __syncthreads();
    int wv = threadIdx.x >> 6, lane = threadIdx.x & 63;
    float br = bih[lane], bz = bih[64 + lane], bn = bih[128 + lane];
    float cr = bhh[lane], cz = bhh[64 + lane], cn = bhh[128 + lane];
    for (int dd = blockIdx.x * 4 + wv; dd < N; dd += gridDim.x * 4) {
        int d = rfl(dd);
        const float* mp = m + (size_t)d * 64;
        const float* hp = xh + (size_t)d * 64;
        float hv = hp[lane];
        float gir = br, giz = bz, gin = bn, ghr = cr, ghz = cz, ghn = cn;
#pragma unroll 2
        for (int k4 = 0; k4 < 16; k4++) {
            int k = k4 * 4;
            float4 m4 = *(const float4*)&mp[k];
            float4 h4 = *(const float4*)&hp[k];
#pragma unroll
            for (int kk = 0; kk < 4; kk++) {
                uint2 wa = Wa[(k + kk) * 64 + lane];
                u32 wb = Wb[(k + kk) * 64 + lane];
                float mk = kk == 0 ? m4.x : kk == 1 ? m4.y : kk == 2 ? m4.z : m4.w;
                float hk = kk == 0 ? h4.x : kk == 1 ? h4.y : kk == 2 ? h4.z : h4.w;
                gir += mk * blo(wa.x); giz += mk * bhi(wa.x); gin += mk * blo(wa.y);
                ghr += hk * bhi(wa.y); ghz += hk * blo(wb); ghn += hk * bhi(wb);
            }
        }
        float r = sigm(gir + ghr);
        float z = sigm(giz + ghz);
        float nn = tanhf(gin + r * ghn);
        xh[(size_t)d * 64 + lane] = (1.f - z) * nn + z * hv;
    }
}

// ---------------- fused Set2Set step, block = 1024 ----------------
__global__ void __launch_bounds__(1024)
k_s2s(const float* __restrict__ xh, const int* __restrict__ gptr,
      float* __restrict__ qstar, float* __restrict__ qh, float* __restrict__ qc,
      const float* __restrict__ lWih, const float* __restrict__ lWhh,
      const float* __restrict__ lbih, const float* __restrict__ lbhh,
      const float* __restrict__ Wr1, const float* __restrict__ br1,
      const float* __restrict__ Wr2, const float* __restrict__ br2,
      float* __restrict__ out, int last) {
    int b = blockIdx.x, tid = threadIdx.x;
    __shared__ float qs[128], qhl[64], g[256], red[16], asums[16], rvs[1024];
    if (tid < 128) qs[tid] = qstar[b * 128 + tid];
    else if (tid < 192) qhl[tid - 128] = qh[b * 64 + tid - 128];
    __syncthreads();
    if (tid < 256) {
        float acc = lbih[tid] + lbhh[tid];
        const float* wr = lWih + tid * 128;
#pragma unroll 8
        for (int k = 0; k < 128; k++) acc += qs[k] * wr[k];
        const float* ur = lWhh + tid * 64;
#pragma unroll 8
        for (int k = 0; k < 64; k++) acc += qhl[k] * ur[k];
        g[tid] = acc;
    }
    __syncthreads();
    if (tid < 64) {
        float ig = sigm(g[tid]), fg = sigm(g[64 + tid]);
        float gg = tanhf(g[128 + tid]), og = sigm(g[192 + tid]);
        float c = fg * qc[b * 64 + tid] + ig * gg;
        float h = og * tanhf(c);
        qc[b * 64 + tid] = c;
        qh[b * 64 + tid] = h;
        qstar[b * 128 + tid] = h;
        qhl[tid] = h;
        qs[tid] = h;
    }
    __syncthreads();
    int grp = tid >> 6, lane = tid & 63;
    int start = gptr[b], end = gptr[b + 1];
    float qv = qhl[lane];
    float mloc = -3.4e38f;
    for (int n = start + grp; n < end; n += 16) {
        float p = xh[(size_t)n * 64 + lane] * qv;
#pragma unroll
        for (int off = 32; off > 0; off >>= 1) p += __shfl_xor(p, off);
        mloc = fmaxf(mloc, p);
    }
    if (lane == 0) red[grp] = mloc;
    __syncthreads();
    float emax = red[0];
#pragma unroll
    for (int j = 1; j < 16; j++) emax = fmaxf(emax, red[j]);
    float asl = 0.f, rv = 0.f;
    for (int n = start + grp; n < end; n += 16) {
        float xv = xh[(size_t)n * 64 + lane];
        float p = xv * qv;
#pragma unroll
        for (int off = 32; off > 0; off >>= 1) p += __shfl_xor(p, off);
        float a = expf(p - emax);
        asl += a;
        rv += a * xv;
    }
    if (lane == 0) asums[grp] = asl;
    rvs[tid] = rv;
    __syncthreads();
    if (tid < 64) {
        float rt = 0.f, at = 0.f;
#pragma unroll
        for (int j = 0; j < 16; j++) { rt += rvs[tid + 64 * j]; at += asums[j]; }
        float rvec = (at > 0.f) ? rt / at : 0.f;
        qstar[b * 128 + 64 + tid] = rvec;
        qs[64 + tid] = rvec;
    }
    if (last) {
        __syncthreads();
        if (tid < 64) {
            float a2 = br1[tid];
#pragma unroll 8
            for (int k = 0; k < 128; k++) a2 += qs[k] * Wr1[k * 64 + tid];
            a2 = fmaxf(a2, 0.f);
            float v = a2 * Wr2[tid];
#pragma unroll
            for (int off = 32; off > 0; off >>= 1) v += __shfl_xor(v, off);
            if (tid == 0) out[b] = v + br2[0];
        }
    }
}

extern "C" void kernel_launch(void* const* d_in, const int* in_sizes, int n_in,
                              void* d_out, int out_size, void* d_ws, size_t ws_size,
                              hipStream_t stream) {
    const float* x_feat = (const float*)d_in[0];
    const int*   ei     = (const int*)d_in[1];
    const float* eattr  = (const float*)d_in[2];
    const int*   batch  = (const int*)d_in[3];
    const float* W_emb  = (const float*)d_in[4];
    const float* b_emb  = (const float*)d_in[5];
    const float* W_m1   = (const float*)d_in[6];
    const float* b_m1   = (const float*)d_in[7];
    const float* W_m2   = (const float*)d_in[8];
    const float* b_m2   = (const float*)d_in[9];
    const float* gWih   = (const float*)d_in[10];
    const float* gWhh   = (const float*)d_in[11];
    const float* gbih   = (const float*)d_in[12];
    const float* gbhh   = (const float*)d_in[13];
    const float* lWih   = (const float*)d_in[14];
    const float* lWhh   = (const float*)d_in[15];
    const float* lbih   = (const float*)d_in[16];
    const float* lbhh   = (const float*)d_in[17];
    const float* Wr1    = (const float*)d_in[18];
    const float* br1    = (const float*)d_in[19];
    const float* Wr2    = (const float*)d_in[20];
    const float* br2    = (const float*)d_in[21];

    int N = in_sizes[0] / NDIM;   // 50000
    int E = in_sizes[1] / 2;      // 800000

    char* w = (char*)d_ws;
    auto alloc = [&](size_t b) { char* p = w; w += (b + 511) & ~(size_t)511; return p; };
    float* xh    = (float*)alloc((size_t)N * 64 * 4);
    float* Ps    = (float*)alloc((size_t)N * 128 * 4);
    float* Hb    = (float*)alloc((size_t)N * 128 * 4);
    float* mb    = (float*)alloc((size_t)N * 64 * 4);
    int*   ptr   = (int*)alloc((size_t)(N + 1) * 4);
    int2*  esl   = (int2*)alloc((size_t)E * 8);
    char* z0 = w;
    int*   cnt    = (int*)alloc((size_t)N * 4);
    int*   cursor = (int*)alloc((size_t)N * 4);
    char* z0e = w;
    int*   gptr  = (int*)alloc((size_t)(NG + 1) * 4);
    char* z1 = w;
    float* qh    = (float*)alloc((size_t)NG * 64 * 4);
    float* qc    = (float*)alloc((size_t)NG * 64 * 4);
    float* qstar = (float*)alloc((size_t)NG * 128 * 4);
    char* z1e = w;

    hipMemsetAsync(z0, 0, (size_t)(z0e - z0), stream);
    hipMemsetAsync(z1, 0, (size_t)(z1e - z1), stream);

    k_hist<<<1024, 256, 0, stream>>>(ei + E, E, cnt);
    k_scan<<<1, 1024, 0, stream>>>(cnt, ptr, N);
    k_gptr<<<3, 256, 0, stream>>>(batch, N, gptr);
    k_scatter<<<3125, 256, 0, stream>>>(ei, ei + E, E, ptr, cursor, esl);

    k_embed<<<2048, 256, 0, stream>>>(x_feat, W_emb, b_emb, xh, N);

    int gprep = ((N + 7) / 8 + 3) / 4;
    for (int r = 0; r < 3; r++) {
        k_prep<<<gprep, 256, 0, stream>>>(xh, W_m1, b_m1, Hb, Ps, N);
        k_edge<<<4096, 256, 0, stream>>>(Ps, eattr, W_m1, ptr, esl, Hb, N);
        k_msg<<<1024, 256, 0, stream>>>(Hb, W_m2, b_m2, ptr, mb, N);
        k_gru<<<1280, 256, 0, stream>>>(mb, gWih, gWhh, gbih, gbhh, xh, N);
    }
    for (int s = 0; s < 6; s++) {
        k_s2s<<<NG, 1024, 0, stream>>>(xh, gptr, qstar, qh, qc,
                                       lWih, lWhh, lbih, lbhh,
                                       Wr1, br1, Wr2, br2, (float*)d_out, s == 5);
    }
}

// Round 6
// 1256.392 us; speedup vs baseline: 4.0525x; 1.1377x over previous
//
#include <hip/hip_runtime.h>
#include <hip/hip_bf16.h>

#define HID 64
#define MSG 128
#define NDIM 32
#define EDIM 16
#define NG 512
#define SCAP 192

typedef unsigned short u16;
typedef unsigned int u32;

__device__ __forceinline__ float b2f(u16 u){union{u32 i;float f;}v;v.i=((u32)u)<<16;return v.f;}
__device__ __forceinline__ u16 f2b(float f){union{float f;u32 i;}v;v.f=f;u32 r=v.i+0x7FFF+((v.i>>16)&1);return (u16)(r>>16);}
__device__ __forceinline__ u32 pack2(float a,float b){return (u32)f2b(a)|((u32)f2b(b)<<16);}
__device__ __forceinline__ float blo(u32 w){union{u32 i;float f;}v;v.i=w<<16;return v.f;}
__device__ __forceinline__ float bhi(u32 w){union{u32 i;float f;}v;v.i=w&0xffff0000u;return v.f;}
__device__ __forceinline__ float sigm(float x){return 1.0f/(1.0f+expf(-x));}
__device__ __forceinline__ int rfl(int x){return __builtin_amdgcn_readfirstlane(x);}

// ---------------- CSR build ----------------
__global__ void k_hist(const int* __restrict__ idx, int n, int* __restrict__ cnt) {
    int i = blockIdx.x * blockDim.x + threadIdx.x;
    int stride = gridDim.x * blockDim.x;
    for (; i < n; i += stride) atomicAdd(&cnt[idx[i]], 1);
}

__global__ void k_scan(const int* __restrict__ in, int* __restrict__ out, int n) {
    __shared__ int sums[1024];
    int tid = threadIdx.x;
    int chunk = (n + 1023) >> 10;
    int begin = tid * chunk;
    int endp = begin + chunk; if (endp > n) endp = n;
    int s = 0;
    for (int i = begin; i < endp; i++) s += in[i];
    sums[tid] = s;
    __syncthreads();
    for (int off = 1; off < 1024; off <<= 1) {
        int t = (tid >= off) ? sums[tid - off] : 0;
        __syncthreads();
        sums[tid] += t;
        __syncthreads();
    }
    int run = sums[tid] - s;
    for (int i = begin; i < endp; i++) { out[i] = run; run += in[i]; }
    if (tid == 1023) out[n] = sums[1023];
}

__global__ void k_gptr(const int* __restrict__ batch, int N, int* __restrict__ gptr) {
    int g = blockIdx.x * blockDim.x + threadIdx.x;
    if (g > NG) return;
    int lo = 0, hi = N;
    while (lo < hi) { int mid = (lo + hi) >> 1; if (batch[mid] < g) lo = mid + 1; else hi = mid; }
    gptr[g] = lo;
}

__global__ void k_scatter(const int* __restrict__ src, const int* __restrict__ dst, int n,
                          const int* __restrict__ ptr, int* __restrict__ cursor,
                          int2* __restrict__ esl) {
    int i = blockIdx.x * blockDim.x + threadIdx.x;
    int stride = gridDim.x * blockDim.x;
    for (; i < n; i += stride) {
        int d = dst[i];
        int pos = ptr[d] + atomicAdd(&cursor[d], 1);
        esl[pos] = make_int2(i, src[i]);
    }
}

// ---------------- GRU weight pre-pack ----------------
__global__ void k_packw(const float* __restrict__ Wih, const float* __restrict__ Whh,
                        uint2* __restrict__ gWa, u32* __restrict__ gWb) {
    int t = blockIdx.x * blockDim.x + threadIdx.x;
    if (t < 64 * 64) {
        int k = t >> 6, c = t & 63;
        gWa[t] = make_uint2(pack2(Wih[c * 64 + k], Wih[(64 + c) * 64 + k]),
                            pack2(Wih[(128 + c) * 64 + k], Whh[c * 64 + k]));
        gWb[t] = pack2(Whh[(64 + c) * 64 + k], Whh[(128 + c) * 64 + k]);
    }
}

// ---------------- node embedding ----------------
__global__ void k_embed(const float* __restrict__ xf, const float* __restrict__ We,
                        const float* __restrict__ be, float* __restrict__ xh, int N) {
    __shared__ float Wl[NDIM * HID];
    for (int t = threadIdx.x; t < NDIM * HID; t += blockDim.x) Wl[t] = We[t];
    __syncthreads();
    int total = N * HID;
    int stride = gridDim.x * blockDim.x;
    for (int idx = blockIdx.x * blockDim.x + threadIdx.x; idx < total; idx += stride) {
        int n = idx >> 6, c = idx & 63;
        const float* xr = xf + n * NDIM;
        float acc = be[c];
#pragma unroll
        for (int k = 0; k < NDIM; k++) acc += xr[k] * Wl[k * HID + c];
        xh[idx] = acc;
    }
}

// ---------------- k_prep: Pd (-> Hb) and Ps ----------------
__global__ void __launch_bounds__(256)
k_prep(const float* __restrict__ xh, const float* __restrict__ Wm1,
       const float* __restrict__ bm1, float* __restrict__ Hb,
       float* __restrict__ Ps, int N) {
    __shared__ float Wl[64 * 256];
    for (int t = threadIdx.x; t < 64 * 256; t += 256) {
        int k = t >> 8, cc = t & 255;
        Wl[t] = (cc < 128) ? Wm1[k * 128 + cc] : Wm1[(64 + k) * 128 + (cc - 128)];
    }
    __syncthreads();
    int wv = threadIdx.x >> 6, lane = threadIdx.x & 63;
    int cc = lane * 4;
    float4 bias;
    if (lane < 32) bias = *(const float4*)&bm1[cc];
    else bias = make_float4(0.f, 0.f, 0.f, 0.f);
    int ngroups = (N + 7) >> 3;
    for (int g = blockIdx.x * 4 + wv; g < ngroups; g += gridDim.x * 4) {
        int base = rfl(g) * 8;
        const float* xp[8];
#pragma unroll
        for (int t = 0; t < 8; t++) {
            int d = base + t; if (d > N - 1) d = N - 1;
            xp[t] = xh + (size_t)d * 64;
        }
        float4 acc[8];
#pragma unroll
        for (int t = 0; t < 8; t++) acc[t] = bias;
#pragma unroll 2
        for (int k4 = 0; k4 < 16; k4++) {
            int k = k4 * 4;
            float4 xv4[8];
#pragma unroll
            for (int t = 0; t < 8; t++) xv4[t] = *(const float4*)&xp[t][k];
#pragma unroll
            for (int kk = 0; kk < 4; kk++) {
                float4 w = *(const float4*)&Wl[(k + kk) * 256 + cc];
#pragma unroll
                for (int t = 0; t < 8; t++) {
                    float xv = kk == 0 ? xv4[t].x : kk == 1 ? xv4[t].y : kk == 2 ? xv4[t].z : xv4[t].w;
                    acc[t].x += xv * w.x; acc[t].y += xv * w.y;
                    acc[t].z += xv * w.z; acc[t].w += xv * w.w;
                }
            }
        }
#pragma unroll
        for (int t = 0; t < 8; t++) {
            int d = base + t;
            if (d < N) {
                if (lane < 32) *(float4*)&Hb[(size_t)d * 128 + cc] = acc[t];
                else *(float4*)&Ps[(size_t)d * 128 + (cc - 128)] = acc[t];
            }
        }
    }
}

// ---------------- k_edge ----------------
__device__ __forceinline__ float edot16(const float* __restrict__ e, const float* w) {
    float4 a = *(const float4*)e;
    float4 b = *(const float4*)(e + 4);
    float4 c4 = *(const float4*)(e + 8);
    float4 d4 = *(const float4*)(e + 12);
    return a.x*w[0] + a.y*w[1] + a.z*w[2] + a.w*w[3]
         + b.x*w[4] + b.y*w[5] + b.z*w[6] + b.w*w[7]
         + c4.x*w[8] + c4.y*w[9] + c4.z*w[10] + c4.w*w[11]
         + d4.x*w[12] + d4.y*w[13] + d4.z*w[14] + d4.w*w[15];
}

__global__ void __launch_bounds__(256)
k_edge(const float* __restrict__ Ps, const float* __restrict__ ea,
       const float* __restrict__ Wm1, const int* __restrict__ ptr,
       const int2* __restrict__ esl, float* __restrict__ Hb, int N) {
    int c = threadIdx.x & 127;
    int half = threadIdx.x >> 7;
    float w[16];
#pragma unroll
    for (int k = 0; k < 16; k++) w[k] = Wm1[128 * 128 + k * 128 + c];
    for (int dd = blockIdx.x * 2 + half; dd < N; dd += gridDim.x * 2) {
        int d = rfl(dd);
        float pd = Hb[(size_t)d * 128 + c];
        int eb = rfl(ptr[d]), ee = rfl(ptr[d + 1]);
        const int2* ep = esl + eb;
        int ne = ee - eb;
        float acc = 0.f;
        int i = 0;
        for (; i + 8 <= ne; i += 8) {
            int e[8], ns[8];
#pragma unroll
            for (int j = 0; j < 8; j++) {
                int2 q = ep[i + j];
                e[j] = rfl(q.x); ns[j] = rfl(q.y);
            }
            float pv[8];
#pragma unroll
            for (int j = 0; j < 8; j++) pv[j] = Ps[(size_t)ns[j] * 128 + c];
#pragma unroll
            for (int j = 0; j < 8; j++) {
                float pe = edot16(ea + (size_t)e[j] * EDIM, w);
                acc += fmaxf(pd + pv[j] + pe, 0.f);
            }
        }
        for (; i < ne; i++) {
            int2 q = ep[i];
            int e0 = rfl(q.x), n0 = rfl(q.y);
            float pv = Ps[(size_t)n0 * 128 + c];
            float pe = edot16(ea + (size_t)e0 * EDIM, w);
            acc += fmaxf(pd + pv + pe, 0.f);
        }
        Hb[(size_t)d * 128 + c] = acc;
    }
}

// ---------------- m = H @ W_m2 + deg*b_m2 ----------------
__global__ void __launch_bounds__(256)
k_msg(const float* __restrict__ H, const float* __restrict__ Wm2,
      const float* __restrict__ bm2, const int* __restrict__ ptr,
      float* __restrict__ m, int N) {
    __shared__ float W2[128 * 64];
    for (int t = threadIdx.x; t < 128 * 64; t += 256) W2[t] = Wm2[t];
    __syncthreads();
    int wv = threadIdx.x >> 6, lane = threadIdx.x & 63;
    float b2 = bm2[lane];
    int ngroups = (N + 3) >> 2;
    for (int g = blockIdx.x * 4 + wv; g < ngroups; g += gridDim.x * 4) {
        int base = rfl(g) * 4;
        const float* hp[4];
#pragma unroll
        for (int t = 0; t < 4; t++) { int d = base + t; if (d > N - 1) d = N - 1; hp[t] = H + (size_t)d * 128; }
        float acc[4] = {0.f, 0.f, 0.f, 0.f};
#pragma unroll 2
        for (int k4 = 0; k4 < 32; k4++) {
            int k = k4 * 4;
            float4 h4[4];
#pragma unroll
            for (int t = 0; t < 4; t++) h4[t] = *(const float4*)&hp[t][k];
#pragma unroll
            for (int kk = 0; kk < 4; kk++) {
                float w = W2[(k + kk) * 64 + lane];
#pragma unroll
                for (int t = 0; t < 4; t++) {
                    float hv = kk == 0 ? h4[t].x : kk == 1 ? h4[t].y : kk == 2 ? h4[t].z : h4[t].w;
                    acc[t] += hv * w;
                }
            }
        }
#pragma unroll
        for (int t = 0; t < 4; t++) {
            int d = base + t;
            if (d < N) {
                float deg = (float)(ptr[d + 1] - ptr[d]);
                m[(size_t)d * 64 + lane] = acc[t] + deg * b2;
            }
        }
    }
}

// ---------------- GRU cell: wave-per-node, pre-packed bf16 weights ----------------
__global__ void __launch_bounds__(256)
k_gru(const float* __restrict__ m, const uint2* __restrict__ gWa,
      const u32* __restrict__ gWb, const float* __restrict__ bih,
      const float* __restrict__ bhh, float* __restrict__ xh, int N) {
    __shared__ uint2 Wa[64 * 64];
    __shared__ u32 Wb[64 * 64];
    {
        const uint4* s1 = (const uint4*)gWa;
        uint4* d1 = (uint4*)Wa;
        for (int t = threadIdx.x; t < 2048; t += 256) d1[t] = s1[t];
        const uint4* s2 = (const uint4*)gWb;
        uint4* d2 = (uint4*)Wb;
        for (int t = threadIdx.x; t < 1024; t += 256) d2[t] = s2[t];
    }
    __syncthreads();
    int wv = threadIdx.x >> 6, lane = threadIdx.x & 63;
    float br = bih[lane], bz = bih[64 + lane], bn = bih[128 + lane];
    float cr = bhh[lane], cz = bhh[64 + lane], cn = bhh[128 + lane];
    for (int dd = blockIdx.x * 4 + wv; dd < N; dd += gridDim.x * 4) {
        int d = rfl(dd);
        const float* mp = m + (size_t)d * 64;
        const float* hp = xh + (size_t)d * 64;
        float hv = hp[lane];
        float gir = br, giz = bz, gin = bn, ghr = cr, ghz = cz, ghn = cn;
#pragma unroll 2
        for (int k4 = 0; k4 < 16; k4++) {
            int k = k4 * 4;
            float4 m4 = *(const float4*)&mp[k];
            float4 h4 = *(const float4*)&hp[k];
#pragma unroll
            for (int kk = 0; kk < 4; kk++) {
                uint2 wa = Wa[(k + kk) * 64 + lane];
                u32 wb = Wb[(k + kk) * 64 + lane];
                float mk = kk == 0 ? m4.x : kk == 1 ? m4.y : kk == 2 ? m4.z : m4.w;
                float hk = kk == 0 ? h4.x : kk == 1 ? h4.y : kk == 2 ? h4.z : h4.w;
                gir += mk * blo(wa.x); giz += mk * bhi(wa.x); gin += mk * blo(wa.y);
                ghr += hk * bhi(wa.y); ghz += hk * blo(wb); ghn += hk * bhi(wb);
            }
        }
        float r = sigm(gir + ghr);
        float z = sigm(giz + ghz);
        float nn = tanhf(gin + r * ghn);
        xh[(size_t)d * 64 + lane] = (1.f - z) * nn + z * hv;
    }
}

// ---------------- fused Set2Set: all 6 steps + final regressor, one block per graph ----------------
__global__ void __launch_bounds__(1024)
k_s2s(const float* __restrict__ xh, const int* __restrict__ gptr,
      const float* __restrict__ lWih, const float* __restrict__ lWhh,
      const float* __restrict__ lbih, const float* __restrict__ lbhh,
      const float* __restrict__ Wr1, const float* __restrict__ br1,
      const float* __restrict__ Wr2, const float* __restrict__ br2,
      float* __restrict__ out) {
    int b = blockIdx.x, tid = threadIdx.x;
    __shared__ float xl[SCAP * 64];
    __shared__ float qs[128], qhl[64], qcs[64], g[256], red[16], asums[16], rvs[1024];
    int start = gptr[b], end = gptr[b + 1];
    int seg = end - start;
    bool uselds = (seg <= SCAP);
    if (uselds) {
        int tot = seg * 64;
        for (int t = tid; t < tot; t += 1024) xl[t] = xh[(size_t)start * 64 + t];
    }
    if (tid < 128) qs[tid] = 0.f;
    if (tid < 64) { qhl[tid] = 0.f; qcs[tid] = 0.f; }
    __syncthreads();
    int grp = tid >> 6, lane = tid & 63;
    for (int s = 0; s < 6; s++) {
        if (tid < 256) {
            float acc = lbih[tid] + lbhh[tid];
            const float* wr = lWih + tid * 128;
#pragma unroll 8
            for (int k = 0; k < 128; k++) acc += qs[k] * wr[k];
            const float* ur = lWhh + tid * 64;
#pragma unroll 8
            for (int k = 0; k < 64; k++) acc += qhl[k] * ur[k];
            g[tid] = acc;
        }
        __syncthreads();
        if (tid < 64) {
            float ig = sigm(g[tid]), fg = sigm(g[64 + tid]);
            float gg = tanhf(g[128 + tid]), og = sigm(g[192 + tid]);
            float c = fg * qcs[tid] + ig * gg;
            float h = og * tanhf(c);
            qcs[tid] = c; qhl[tid] = h; qs[tid] = h;
        }
        __syncthreads();
        float qv = qhl[lane];
        float mloc = -3.4e38f;
        for (int n = grp; n < seg; n += 16) {
            float xv = uselds ? xl[n * 64 + lane] : xh[(size_t)(start + n) * 64 + lane];
            float p = xv * qv;
#pragma unroll
            for (int off = 32; off > 0; off >>= 1) p += __shfl_xor(p, off);
            mloc = fmaxf(mloc, p);
        }
        if (lane == 0) red[grp] = mloc;
        __syncthreads();
        float emax = red[0];
#pragma unroll
        for (int j = 1; j < 16; j++) emax = fmaxf(emax, red[j]);
        float asl = 0.f, rv = 0.f;
        for (int n = grp; n < seg; n += 16) {
            float xv = uselds ? xl[n * 64 + lane] : xh[(size_t)(start + n) * 64 + lane];
            float p = xv * qv;
#pragma unroll
            for (int off = 32; off > 0; off >>= 1) p += __shfl_xor(p, off);
            float a = expf(p - emax);
            asl += a;
            rv += a * xv;
        }
        if (lane == 0) asums[grp] = asl;
        rvs[tid] = rv;
        __syncthreads();
        if (tid < 64) {
            float rt = 0.f, at = 0.f;
#pragma unroll
            for (int j = 0; j < 16; j++) { rt += rvs[tid + 64 * j]; at += asums[j]; }
            qs[64 + tid] = (at > 0.f) ? rt / at : 0.f;
        }
        __syncthreads();
    }
    if (tid < 64) {
        float a2 = br1[tid];
#pragma unroll 8
        for (int k = 0; k < 128; k++) a2 += qs[k] * Wr1[k * 64 + tid];
        a2 = fmaxf(a2, 0.f);
        float v = a2 * Wr2[tid];
#pragma unroll
        for (int off = 32; off > 0; off >>= 1) v += __shfl_xor(v, off);
        if (tid == 0) out[b] = v + br2[0];
    }
}

extern "C" void kernel_launch(void* const* d_in, const int* in_sizes, int n_in,
                              void* d_out, int out_size, void* d_ws, size_t ws_size,
                              hipStream_t stream) {
    const float* x_feat = (const float*)d_in[0];
    const int*   ei     = (const int*)d_in[1];
    const float* eattr  = (const float*)d_in[2];
    const int*   batch  = (const int*)d_in[3];
    const float* W_emb  = (const float*)d_in[4];
    const float* b_emb  = (const float*)d_in[5];
    const float* W_m1   = (const float*)d_in[6];
    const float* b_m1   = (const float*)d_in[7];
    const float* W_m2   = (const float*)d_in[8];
    const float* b_m2   = (const float*)d_in[9];
    const float* gWih   = (const float*)d_in[10];
    const float* gWhh   = (const float*)d_in[11];
    const float* gbih   = (const float*)d_in[12];
    const float* gbhh   = (const float*)d_in[13];
    const float* lWih   = (const float*)d_in[14];
    const float* lWhh   = (const float*)d_in[15];
    const float* lbih   = (const float*)d_in[16];
    const float* lbhh   = (const float*)d_in[17];
    const float* Wr1    = (const float*)d_in[18];
    const float* br1    = (const float*)d_in[19];
    const float* Wr2    = (const float*)d_in[20];
    const float* br2    = (const float*)d_in[21];

    int N = in_sizes[0] / NDIM;   // 50000
    int E = in_sizes[1] / 2;      // 800000

    char* w = (char*)d_ws;
    auto alloc = [&](size_t b) { char* p = w; w += (b + 511) & ~(size_t)511; return p; };
    float* xh    = (float*)alloc((size_t)N * 64 * 4);
    float* Ps    = (float*)alloc((size_t)N * 128 * 4);
    float* Hb    = (float*)alloc((size_t)N * 128 * 4);
    float* mb    = (float*)alloc((size_t)N * 64 * 4);
    int*   ptr   = (int*)alloc((size_t)(N + 1) * 4);
    int2*  esl   = (int2*)alloc((size_t)E * 8);
    uint2* gWa   = (uint2*)alloc((size_t)4096 * 8);
    u32*   gWb   = (u32*)alloc((size_t)4096 * 4);
    char* z0 = w;
    int*   cnt    = (int*)alloc((size_t)N * 4);
    int*   cursor = (int*)alloc((size_t)N * 4);
    char* z0e = w;
    int*   gptr  = (int*)alloc((size_t)(NG + 1) * 4);

    hipMemsetAsync(z0, 0, (size_t)(z0e - z0), stream);

    k_hist<<<1024, 256, 0, stream>>>(ei + E, E, cnt);
    k_scan<<<1, 1024, 0, stream>>>(cnt, ptr, N);
    k_gptr<<<3, 256, 0, stream>>>(batch, N, gptr);
    k_scatter<<<3125, 256, 0, stream>>>(ei, ei + E, E, ptr, cursor, esl);
    k_packw<<<16, 256, 0, stream>>>(gWih, gWhh, gWa, gWb);

    k_embed<<<2048, 256, 0, stream>>>(x_feat, W_emb, b_emb, xh, N);

    int gprep = ((N + 7) / 8 + 3) / 4;
    for (int r = 0; r < 3; r++) {
        k_prep<<<gprep, 256, 0, stream>>>(xh, W_m1, b_m1, Hb, Ps, N);
        k_edge<<<4096, 256, 0, stream>>>(Ps, eattr, W_m1, ptr, esl, Hb, N);
        k_msg<<<1024, 256, 0, stream>>>(Hb, W_m2, b_m2, ptr, mb, N);
        k_gru<<<1280, 256, 0, stream>>>(mb, gWa, gWb, gbih, gbhh, xh, N);
    }
    k_s2s<<<NG, 1024, 0, stream>>>(xh, gptr, lWih, lWhh, lbih, lbhh,
                                   Wr1, br1, Wr2, br2, (float*)d_out);
}

// Round 7
// 1200.708 us; speedup vs baseline: 4.2404x; 1.0464x over previous
//
#include <hip/hip_runtime.h>
#include <hip/hip_bf16.h>

#define HID 64
#define MSG 128
#define NDIM 32
#define EDIM 16
#define NG 512
#define SCAP 192

typedef unsigned short u16;
typedef unsigned int u32;
typedef _Float16 h8 __attribute__((ext_vector_type(8)));
typedef _Float16 h4 __attribute__((ext_vector_type(4)));

__device__ __forceinline__ u16 f2b(float f){union{float f;u32 i;}v;v.f=f;u32 r=v.i+0x7FFF+((v.i>>16)&1);return (u16)(r>>16);}
__device__ __forceinline__ u32 pack2(float a,float b){return (u32)f2b(a)|((u32)f2b(b)<<16);}
__device__ __forceinline__ float blo(u32 w){union{u32 i;float f;}v;v.i=w<<16;return v.f;}
__device__ __forceinline__ float bhi(u32 w){union{u32 i;float f;}v;v.i=w&0xffff0000u;return v.f;}
__device__ __forceinline__ float sigm(float x){return 1.0f/(1.0f+expf(-x));}
__device__ __forceinline__ int rfl(int x){return __builtin_amdgcn_readfirstlane(x);}

// ---------------- CSR build ----------------
__global__ void k_hist(const int* __restrict__ idx, int n, int* __restrict__ cnt) {
    int i = blockIdx.x * blockDim.x + threadIdx.x;
    int stride = gridDim.x * blockDim.x;
    for (; i < n; i += stride) atomicAdd(&cnt[idx[i]], 1);
}

// 3-phase scan: A = per-1024-block exclusive scan, B = scan block sums, C = add offsets
__global__ void k_scanA(const int* __restrict__ in, int* __restrict__ out,
                        int* __restrict__ bsum, int n) {
    __shared__ int sh[1024];
    int i = blockIdx.x * 1024 + threadIdx.x;
    int v = (i < n) ? in[i] : 0;
    sh[threadIdx.x] = v;
    __syncthreads();
    for (int off = 1; off < 1024; off <<= 1) {
        int t = (threadIdx.x >= off) ? sh[threadIdx.x - off] : 0;
        __syncthreads();
        sh[threadIdx.x] += t;
        __syncthreads();
    }
    if (i < n) out[i] = sh[threadIdx.x] - v;
    if (threadIdx.x == 1023) bsum[blockIdx.x] = sh[1023];
}
__global__ void k_scanB(const int* __restrict__ bsum, int* __restrict__ boff, int nb) {
    if (threadIdx.x == 0) {
        int r = 0;
        for (int b = 0; b < nb; b++) { boff[b] = r; r += bsum[b]; }
        boff[nb] = r;
    }
}
__global__ void k_scanC(int* __restrict__ out, const int* __restrict__ boff, int n, int nb) {
    int i = blockIdx.x * blockDim.x + threadIdx.x;
    if (i < n) out[i] += boff[i >> 10];
    else if (i == n) out[n] = boff[nb];
}

__global__ void k_gptr(const int* __restrict__ batch, int N, int* __restrict__ gptr) {
    int g = blockIdx.x * blockDim.x + threadIdx.x;
    if (g > NG) return;
    int lo = 0, hi = N;
    while (lo < hi) { int mid = (lo + hi) >> 1; if (batch[mid] < g) lo = mid + 1; else hi = mid; }
    gptr[g] = lo;
}

__global__ void k_scatter(const int* __restrict__ src, const int* __restrict__ dst, int n,
                          const int* __restrict__ ptr, int* __restrict__ cursor,
                          int* __restrict__ eidx, int* __restrict__ slist) {
    int i = blockIdx.x * blockDim.x + threadIdx.x;
    int stride = gridDim.x * blockDim.x;
    for (; i < n; i += stride) {
        int d = dst[i];
        int pos = ptr[d] + atomicAdd(&cursor[d], 1);
        eidx[pos] = i;
        slist[pos] = src[i];
    }
}

// permute edge_attr into CSR order, fp16. one edge (16 attrs) per thread.
__global__ void k_permea(const int* __restrict__ eidx, const float* __restrict__ ea,
                         _Float16* __restrict__ eap, int E) {
    int i = blockIdx.x * blockDim.x + threadIdx.x;
    if (i >= E) return;
    int e = eidx[i];
    const float* s = ea + (size_t)e * EDIM;
    float4 a = *(const float4*)s, b = *(const float4*)(s + 4);
    float4 c = *(const float4*)(s + 8), d = *(const float4*)(s + 12);
    h8 o0, o1;
    o0[0]=(_Float16)a.x; o0[1]=(_Float16)a.y; o0[2]=(_Float16)a.z; o0[3]=(_Float16)a.w;
    o0[4]=(_Float16)b.x; o0[5]=(_Float16)b.y; o0[6]=(_Float16)b.z; o0[7]=(_Float16)b.w;
    o1[0]=(_Float16)c.x; o1[1]=(_Float16)c.y; o1[2]=(_Float16)c.z; o1[3]=(_Float16)c.w;
    o1[4]=(_Float16)d.x; o1[5]=(_Float16)d.y; o1[6]=(_Float16)d.z; o1[7]=(_Float16)d.w;
    h8* dp = (h8*)(eap + (size_t)i * EDIM);
    dp[0] = o0; dp[1] = o1;
}

// ---------------- GRU weight pre-pack ----------------
__global__ void k_packw(const float* __restrict__ Wih, const float* __restrict__ Whh,
                        uint2* __restrict__ gWa, u32* __restrict__ gWb) {
    int t = blockIdx.x * blockDim.x + threadIdx.x;
    if (t < 64 * 64) {
        int k = t >> 6, c = t & 63;
        gWa[t] = make_uint2(pack2(Wih[c * 64 + k], Wih[(64 + c) * 64 + k]),
                            pack2(Wih[(128 + c) * 64 + k], Whh[c * 64 + k]));
        gWb[t] = pack2(Whh[(64 + c) * 64 + k], Whh[(128 + c) * 64 + k]);
    }
}

// ---------------- node embedding ----------------
__global__ void k_embed(const float* __restrict__ xf, const float* __restrict__ We,
                        const float* __restrict__ be, float* __restrict__ xh, int N) {
    __shared__ float Wl[NDIM * HID];
    for (int t = threadIdx.x; t < NDIM * HID; t += blockDim.x) Wl[t] = We[t];
    __syncthreads();
    int total = N * HID;
    int stride = gridDim.x * blockDim.x;
    for (int idx = blockIdx.x * blockDim.x + threadIdx.x; idx < total; idx += stride) {
        int n = idx >> 6, c = idx & 63;
        const float* xr = xf + n * NDIM;
        float acc = be[c];
#pragma unroll
        for (int k = 0; k < NDIM; k++) acc += xr[k] * Wl[k * HID + c];
        xh[idx] = acc;
    }
}

// ---------------- k_prep: Pd (-> Hb, f32) and Ps (f16) ----------------
__global__ void __launch_bounds__(256)
k_prep(const float* __restrict__ xh, const float* __restrict__ Wm1,
       const float* __restrict__ bm1, float* __restrict__ Hb,
       _Float16* __restrict__ PsH, int N) {
    __shared__ float Wl[64 * 256];
    for (int t = threadIdx.x; t < 64 * 256; t += 256) {
        int k = t >> 8, cc = t & 255;
        Wl[t] = (cc < 128) ? Wm1[k * 128 + cc] : Wm1[(64 + k) * 128 + (cc - 128)];
    }
    __syncthreads();
    int wv = threadIdx.x >> 6, lane = threadIdx.x & 63;
    int cc = lane * 4;
    float4 bias;
    if (lane < 32) bias = *(const float4*)&bm1[cc];
    else bias = make_float4(0.f, 0.f, 0.f, 0.f);
    int ngroups = (N + 7) >> 3;
    for (int g = blockIdx.x * 4 + wv; g < ngroups; g += gridDim.x * 4) {
        int base = rfl(g) * 8;
        const float* xp[8];
#pragma unroll
        for (int t = 0; t < 8; t++) {
            int d = base + t; if (d > N - 1) d = N - 1;
            xp[t] = xh + (size_t)d * 64;
        }
        float4 acc[8];
#pragma unroll
        for (int t = 0; t < 8; t++) acc[t] = bias;
#pragma unroll 2
        for (int k4 = 0; k4 < 16; k4++) {
            int k = k4 * 4;
            float4 xv4[8];
#pragma unroll
            for (int t = 0; t < 8; t++) xv4[t] = *(const float4*)&xp[t][k];
#pragma unroll
            for (int kk = 0; kk < 4; kk++) {
                float4 w = *(const float4*)&Wl[(k + kk) * 256 + cc];
#pragma unroll
                for (int t = 0; t < 8; t++) {
                    float xv = kk == 0 ? xv4[t].x : kk == 1 ? xv4[t].y : kk == 2 ? xv4[t].z : xv4[t].w;
                    acc[t].x += xv * w.x; acc[t].y += xv * w.y;
                    acc[t].z += xv * w.z; acc[t].w += xv * w.w;
                }
            }
        }
#pragma unroll
        for (int t = 0; t < 8; t++) {
            int d = base + t;
            if (d < N) {
                if (lane < 32) *(float4*)&Hb[(size_t)d * 128 + cc] = acc[t];
                else {
                    h4 o;
                    o[0] = (_Float16)acc[t].x; o[1] = (_Float16)acc[t].y;
                    o[2] = (_Float16)acc[t].z; o[3] = (_Float16)acc[t].w;
                    *(h4*)&PsH[(size_t)d * 128 + (cc - 128)] = o;
                }
            }
        }
    }
}

// ---------------- k_edge ----------------
__device__ __forceinline__ float edot16h(const _Float16* __restrict__ e, const float* w) {
    h8 a = *(const h8*)e, b = *(const h8*)(e + 8);
    float s = 0.f;
#pragma unroll
    for (int k = 0; k < 8; k++) s += (float)a[k] * w[k];
#pragma unroll
    for (int k = 0; k < 8; k++) s += (float)b[k] * w[8 + k];
    return s;
}

__global__ void __launch_bounds__(256)
k_edge(const _Float16* __restrict__ PsH, const _Float16* __restrict__ eap,
       const float* __restrict__ Wm1, const int* __restrict__ ptr,
       const int* __restrict__ slist, float* __restrict__ Hb, int N) {
    int c = threadIdx.x & 127;
    int half = threadIdx.x >> 7;
    float w[16];
#pragma unroll
    for (int k = 0; k < 16; k++) w[k] = Wm1[128 * 128 + k * 128 + c];
    for (int dd = blockIdx.x * 2 + half; dd < N; dd += gridDim.x * 2) {
        int d = rfl(dd);
        float pd = Hb[(size_t)d * 128 + c];
        int eb = rfl(ptr[d]), ee = rfl(ptr[d + 1]);
        const int* sp = slist + eb;
        const _Float16* ep = eap + (size_t)eb * EDIM;
        int ne = ee - eb;
        float acc = 0.f;
        int i = 0;
        for (; i + 8 <= ne; i += 8) {
            int ns[8];
#pragma unroll
            for (int j = 0; j < 8; j++) ns[j] = rfl(sp[i + j]);
            float pv[8];
#pragma unroll
            for (int j = 0; j < 8; j++) pv[j] = (float)PsH[(size_t)ns[j] * 128 + c];
#pragma unroll
            for (int j = 0; j < 8; j++) {
                float pe = edot16h(ep + (size_t)(i + j) * EDIM, w);
                acc += fmaxf(pd + pv[j] + pe, 0.f);
            }
        }
        for (; i < ne; i++) {
            int n0 = rfl(sp[i]);
            float pv = (float)PsH[(size_t)n0 * 128 + c];
            float pe = edot16h(ep + (size_t)i * EDIM, w);
            acc += fmaxf(pd + pv + pe, 0.f);
        }
        Hb[(size_t)d * 128 + c] = acc;
    }
}

// ---------------- m = H @ W_m2 + deg*b_m2 ----------------
__global__ void __launch_bounds__(256)
k_msg(const float* __restrict__ H, const float* __restrict__ Wm2,
      const float* __restrict__ bm2, const int* __restrict__ ptr,
      float* __restrict__ m, int N) {
    __shared__ float W2[128 * 64];
    for (int t = threadIdx.x; t < 128 * 64; t += 256) W2[t] = Wm2[t];
    __syncthreads();
    int wv = threadIdx.x >> 6, lane = threadIdx.x & 63;
    float b2 = bm2[lane];
    int ngroups = (N + 3) >> 2;
    for (int g = blockIdx.x * 4 + wv; g < ngroups; g += gridDim.x * 4) {
        int base = rfl(g) * 4;
        const float* hp[4];
#pragma unroll
        for (int t = 0; t < 4; t++) { int d = base + t; if (d > N - 1) d = N - 1; hp[t] = H + (size_t)d * 128; }
        float acc[4] = {0.f, 0.f, 0.f, 0.f};
#pragma unroll 2
        for (int k4 = 0; k4 < 32; k4++) {
            int k = k4 * 4;
            float4 h4v[4];
#pragma unroll
            for (int t = 0; t < 4; t++) h4v[t] = *(const float4*)&hp[t][k];
#pragma unroll
            for (int kk = 0; kk < 4; kk++) {
                float w = W2[(k + kk) * 64 + lane];
#pragma unroll
                for (int t = 0; t < 4; t++) {
                    float hv = kk == 0 ? h4v[t].x : kk == 1 ? h4v[t].y : kk == 2 ? h4v[t].z : h4v[t].w;
                    acc[t] += hv * w;
                }
            }
        }
#pragma unroll
        for (int t = 0; t < 4; t++) {
            int d = base + t;
            if (d < N) {
                float deg = (float)(ptr[d + 1] - ptr[d]);
                m[(size_t)d * 64 + lane] = acc[t] + deg * b2;
            }
        }
    }
}

// ---------------- GRU cell: wave-per-node, pre-packed bf16 weights ----------------
__global__ void __launch_bounds__(256)
k_gru(const float* __restrict__ m, const uint2* __restrict__ gWa,
      const u32* __restrict__ gWb, const float* __restrict__ bih,
      const float* __restrict__ bhh, float* __restrict__ xh, int N) {
    __shared__ uint2 Wa[64 * 64];
    __shared__ u32 Wb[64 * 64];
    {
        const uint4* s1 = (const uint4*)gWa;
        uint4* d1 = (uint4*)Wa;
        for (int t = threadIdx.x; t < 2048; t += 256) d1[t] = s1[t];
        const uint4* s2 = (const uint4*)gWb;
        uint4* d2 = (uint4*)Wb;
        for (int t = threadIdx.x; t < 1024; t += 256) d2[t] = s2[t];
    }
    __syncthreads();
    int wv = threadIdx.x >> 6, lane = threadIdx.x & 63;
    float br = bih[lane], bz = bih[64 + lane], bn = bih[128 + lane];
    float cr = bhh[lane], cz = bhh[64 + lane], cn = bhh[128 + lane];
    for (int dd = blockIdx.x * 4 + wv; dd < N; dd += gridDim.x * 4) {
        int d = rfl(dd);
        const float* mp = m + (size_t)d * 64;
        const float* hp = xh + (size_t)d * 64;
        float hv = hp[lane];
        float gir = br, giz = bz, gin = bn, ghr = cr, ghz = cz, ghn = cn;
#pragma unroll 2
        for (int k4 = 0; k4 < 16; k4++) {
            int k = k4 * 4;
            float4 m4 = *(const float4*)&mp[k];
            float4 h4v = *(const float4*)&hp[k];
#pragma unroll
            for (int kk = 0; kk < 4; kk++) {
                uint2 wa = Wa[(k + kk) * 64 + lane];
                u32 wb = Wb[(k + kk) * 64 + lane];
                float mk = kk == 0 ? m4.x : kk == 1 ? m4.y : kk == 2 ? m4.z : m4.w;
                float hk = kk == 0 ? h4v.x : kk == 1 ? h4v.y : kk == 2 ? h4v.z : h4v.w;
                gir += mk * blo(wa.x); giz += mk * bhi(wa.x); gin += mk * blo(wa.y);
                ghr += hk * bhi(wa.y); ghz += hk * blo(wb); ghn += hk * bhi(wb);
            }
        }
        float r = sigm(gir + ghr);
        float z = sigm(giz + ghz);
        float nn = tanhf(gin + r * ghn);
        xh[(size_t)d * 64 + lane] = (1.f - z) * nn + z * hv;
    }
}

// ---------------- fused Set2Set: all 6 steps + final regressor ----------------
__global__ void __launch_bounds__(1024)
k_s2s(const float* __restrict__ xh, const int* __restrict__ gptr,
      const float* __restrict__ lWih, const float* __restrict__ lWhh,
      const float* __restrict__ lbih, const float* __restrict__ lbhh,
      const float* __restrict__ Wr1, const float* __restrict__ br1,
      const float* __restrict__ Wr2, const float* __restrict__ br2,
      float* __restrict__ out) {
    int b = blockIdx.x, tid = threadIdx.x;
    __shared__ float xl[SCAP * 64];
    __shared__ float qs[128], qhl[64], qcs[64], g[256], red[16], asums[16], rvs[1024];
    int start = gptr[b], end = gptr[b + 1];
    int seg = end - start;
    bool uselds = (seg <= SCAP);
    if (uselds) {
        int tot = seg * 64;
        for (int t = tid; t < tot; t += 1024) xl[t] = xh[(size_t)start * 64 + t];
    }
    if (tid < 128) qs[tid] = 0.f;
    if (tid < 64) { qhl[tid] = 0.f; qcs[tid] = 0.f; }
    __syncthreads();
    int grp = tid >> 6, lane = tid & 63;
    for (int s = 0; s < 6; s++) {
        if (tid < 256) {
            float acc = lbih[tid] + lbhh[tid];
            const float* wr = lWih + tid * 128;
#pragma unroll 8
            for (int k = 0; k < 128; k++) acc += qs[k] * wr[k];
            const float* ur = lWhh + tid * 64;
#pragma unroll 8
            for (int k = 0; k < 64; k++) acc += qhl[k] * ur[k];
            g[tid] = acc;
        }
        __syncthreads();
        if (tid < 64) {
            float ig = sigm(g[tid]), fg = sigm(g[64 + tid]);
            float gg = tanhf(g[128 + tid]), og = sigm(g[192 + tid]);
            float c = fg * qcs[tid] + ig * gg;
            float h = og * tanhf(c);
            qcs[tid] = c; qhl[tid] = h; qs[tid] = h;
        }
        __syncthreads();
        float qv = qhl[lane];
        float mloc = -3.4e38f;
        for (int n = grp; n < seg; n += 16) {
            float xv = uselds ? xl[n * 64 + lane] : xh[(size_t)(start + n) * 64 + lane];
            float p = xv * qv;
#pragma unroll
            for (int off = 32; off > 0; off >>= 1) p += __shfl_xor(p, off);
            mloc = fmaxf(mloc, p);
        }
        if (lane == 0) red[grp] = mloc;
        __syncthreads();
        float emax = red[0];
#pragma unroll
        for (int j = 1; j < 16; j++) emax = fmaxf(emax, red[j]);
        float asl = 0.f, rv = 0.f;
        for (int n = grp; n < seg; n += 16) {
            float xv = uselds ? xl[n * 64 + lane] : xh[(size_t)(start + n) * 64 + lane];
            float p = xv * qv;
#pragma unroll
            for (int off = 32; off > 0; off >>= 1) p += __shfl_xor(p, off);
            float a = expf(p - emax);
            asl += a;
            rv += a * xv;
        }
        if (lane == 0) asums[grp] = asl;
        rvs[tid] = rv;
        __syncthreads();
        if (tid < 64) {
            float rt = 0.f, at = 0.f;
#pragma unroll
            for (int j = 0; j < 16; j++) { rt += rvs[tid + 64 * j]; at += asums[j]; }
            qs[64 + tid] = (at > 0.f) ? rt / at : 0.f;
        }
        __syncthreads();
    }
    if (tid < 64) {
        float a2 = br1[tid];
#pragma unroll 8
        for (int k = 0; k < 128; k++) a2 += qs[k] * Wr1[k * 64 + tid];
        a2 = fmaxf(a2, 0.f);
        float v = a2 * Wr2[tid];
#pragma unroll
        for (int off = 32; off > 0; off >>= 1) v += __shfl_xor(v, off);
        if (tid == 0) out[b] = v + br2[0];
    }
}

extern "C" void kernel_launch(void* const* d_in, const int* in_sizes, int n_in,
                              void* d_out, int out_size, void* d_ws, size_t ws_size,
                              hipStream_t stream) {
    const float* x_feat = (const float*)d_in[0];
    const int*   ei     = (const int*)d_in[1];
    const float* eattr  = (const float*)d_in[2];
    const int*   batch  = (const int*)d_in[3];
    const float* W_emb  = (const float*)d_in[4];
    const float* b_emb  = (const float*)d_in[5];
    const float* W_m1   = (const float*)d_in[6];
    const float* b_m1   = (const float*)d_in[7];
    const float* W_m2   = (const float*)d_in[8];
    const float* b_m2   = (const float*)d_in[9];
    const float* gWih   = (const float*)d_in[10];
    const float* gWhh   = (const float*)d_in[11];
    const float* gbih   = (const float*)d_in[12];
    const float* gbhh   = (const float*)d_in[13];
    const float* lWih   = (const float*)d_in[14];
    const float* lWhh   = (const float*)d_in[15];
    const float* lbih   = (const float*)d_in[16];
    const float* lbhh   = (const float*)d_in[17];
    const float* Wr1    = (const float*)d_in[18];
    const float* br1    = (const float*)d_in[19];
    const float* Wr2    = (const float*)d_in[20];
    const float* br2    = (const float*)d_in[21];

    int N = in_sizes[0] / NDIM;   // 50000
    int E = in_sizes[1] / 2;      // 800000

    char* w = (char*)d_ws;
    auto alloc = [&](size_t b) { char* p = w; w += (b + 511) & ~(size_t)511; return p; };
    float*     xh    = (float*)alloc((size_t)N * 64 * 4);
    _Float16*  PsH   = (_Float16*)alloc((size_t)N * 128 * 2);
    float*     Hb    = (float*)alloc((size_t)N * 128 * 4);
    int*       ptr   = (int*)alloc((size_t)(N + 1) * 4);
    int*       slist = (int*)alloc((size_t)E * 4);
    _Float16*  eap   = (_Float16*)alloc((size_t)E * EDIM * 2);
    uint2*     gWa   = (uint2*)alloc((size_t)4096 * 8);
    u32*       gWb   = (u32*)alloc((size_t)4096 * 4);
    int*       gptr  = (int*)alloc((size_t)(NG + 1) * 4);
    int*       bsum  = (int*)alloc(128 * 4);
    int*       boff  = (int*)alloc(128 * 4);
    char* z0 = w;
    int*       cnt    = (int*)alloc((size_t)N * 4);
    int*       cursor = (int*)alloc((size_t)N * 4);
    char* z0e = w;
    // mb aliases eidx: eidx dead after k_permea, mb first written in k_msg
    char*      mbase = alloc((size_t)N * 64 * 4);
    float*     mb    = (float*)mbase;
    int*       eidx  = (int*)mbase;

    hipMemsetAsync(z0, 0, (size_t)(z0e - z0), stream);

    int NB = (N + 1023) / 1024;  // scan blocks
    k_hist<<<1024, 256, 0, stream>>>(ei + E, E, cnt);
    k_scanA<<<NB, 1024, 0, stream>>>(cnt, ptr, bsum, N);
    k_scanB<<<1, 64, 0, stream>>>(bsum, boff, NB);
    k_scanC<<<(N + 256) / 256, 256, 0, stream>>>(ptr, boff, N, NB);
    k_gptr<<<3, 256, 0, stream>>>(batch, N, gptr);
    k_scatter<<<3125, 256, 0, stream>>>(ei, ei + E, E, ptr, cursor, eidx, slist);
    k_permea<<<(E + 255) / 256, 256, 0, stream>>>(eidx, eattr, eap, E);
    k_packw<<<16, 256, 0, stream>>>(gWih, gWhh, gWa, gWb);

    k_embed<<<2048, 256, 0, stream>>>(x_feat, W_emb, b_emb, xh, N);

    for (int r = 0; r < 3; r++) {
        k_prep<<<391, 256, 0, stream>>>(xh, W_m1, b_m1, Hb, PsH, N);
        k_edge<<<4096, 256, 0, stream>>>(PsH, eap, W_m1, ptr, slist, Hb, N);
        k_msg<<<1024, 256, 0, stream>>>(Hb, W_m2, b_m2, ptr, mb, N);
        k_gru<<<1280, 256, 0, stream>>>(mb, gWa, gWb, gbih, gbhh, xh, N);
    }
    k_s2s<<<NG, 1024, 0, stream>>>(xh, gptr, lWih, lWhh, lbih, lbhh,
                                   Wr1, br1, Wr2, br2, (float*)d_out);
}

// Round 8
// 1043.723 us; speedup vs baseline: 4.8782x; 1.1504x over previous
//
#include <hip/hip_runtime.h>
#include <hip/hip_bf16.h>

#define HID 64
#define MSG 128
#define NDIM 32
#define EDIM 16
#define NG 512
#define SCAP 192

typedef unsigned short u16;
typedef unsigned int u32;
typedef _Float16 h8 __attribute__((ext_vector_type(8)));
typedef _Float16 h4 __attribute__((ext_vector_type(4)));
typedef _Float16 h2 __attribute__((ext_vector_type(2)));

__device__ __forceinline__ u16 f2b(float f){union{float f;u32 i;}v;v.f=f;u32 r=v.i+0x7FFF+((v.i>>16)&1);return (u16)(r>>16);}
__device__ __forceinline__ u32 pack2(float a,float b){return (u32)f2b(a)|((u32)f2b(b)<<16);}
__device__ __forceinline__ float blo(u32 w){union{u32 i;float f;}v;v.i=w<<16;return v.f;}
__device__ __forceinline__ float bhi(u32 w){union{u32 i;float f;}v;v.i=w&0xffff0000u;return v.f;}
__device__ __forceinline__ float sigm(float x){return 1.0f/(1.0f+expf(-x));}
__device__ __forceinline__ int rfl(int x){return __builtin_amdgcn_readfirstlane(x);}

// ---------------- CSR build ----------------
__global__ void k_hist(const int* __restrict__ idx, int n, int* __restrict__ cnt) {
    int i = blockIdx.x * blockDim.x + threadIdx.x;
    int stride = gridDim.x * blockDim.x;
    for (; i < n; i += stride) atomicAdd(&cnt[idx[i]], 1);
}

__global__ void k_scanA(const int* __restrict__ in, int* __restrict__ out,
                        int* __restrict__ bsum, int n) {
    __shared__ int sh[1024];
    int i = blockIdx.x * 1024 + threadIdx.x;
    int v = (i < n) ? in[i] : 0;
    sh[threadIdx.x] = v;
    __syncthreads();
    for (int off = 1; off < 1024; off <<= 1) {
        int t = (threadIdx.x >= off) ? sh[threadIdx.x - off] : 0;
        __syncthreads();
        sh[threadIdx.x] += t;
        __syncthreads();
    }
    if (i < n) out[i] = sh[threadIdx.x] - v;
    if (threadIdx.x == 1023) bsum[blockIdx.x] = sh[1023];
}
__global__ void k_scanB(const int* __restrict__ bsum, int* __restrict__ boff, int nb) {
    if (threadIdx.x == 0) {
        int r = 0;
        for (int b = 0; b < nb; b++) { boff[b] = r; r += bsum[b]; }
        boff[nb] = r;
    }
}
__global__ void k_scanC(int* __restrict__ out, const int* __restrict__ boff, int n, int nb) {
    int i = blockIdx.x * blockDim.x + threadIdx.x;
    if (i < n) out[i] += boff[i >> 10];
    else if (i == n) out[n] = boff[nb];
}

__global__ void k_gptr(const int* __restrict__ batch, int N, int* __restrict__ gptr) {
    int g = blockIdx.x * blockDim.x + threadIdx.x;
    if (g > NG) return;
    int lo = 0, hi = N;
    while (lo < hi) { int mid = (lo + hi) >> 1; if (batch[mid] < g) lo = mid + 1; else hi = mid; }
    gptr[g] = lo;
}

__global__ void k_scatter(const int* __restrict__ src, const int* __restrict__ dst, int n,
                          const int* __restrict__ ptr, int* __restrict__ cursor,
                          int* __restrict__ eidx, int* __restrict__ slist) {
    int i = blockIdx.x * blockDim.x + threadIdx.x;
    int stride = gridDim.x * blockDim.x;
    for (; i < n; i += stride) {
        int d = dst[i];
        int pos = ptr[d] + atomicAdd(&cursor[d], 1);
        eidx[pos] = i;
        slist[pos] = src[i];
    }
}

// permute edge_attr into CSR order, fp16
__global__ void k_permea(const int* __restrict__ eidx, const float* __restrict__ ea,
                         _Float16* __restrict__ eap, int E) {
    int i = blockIdx.x * blockDim.x + threadIdx.x;
    if (i >= E) return;
    int e = eidx[i];
    const float* s = ea + (size_t)e * EDIM;
    float4 a = *(const float4*)s, b = *(const float4*)(s + 4);
    float4 c = *(const float4*)(s + 8), d = *(const float4*)(s + 12);
    h8 o0, o1;
    o0[0]=(_Float16)a.x; o0[1]=(_Float16)a.y; o0[2]=(_Float16)a.z; o0[3]=(_Float16)a.w;
    o0[4]=(_Float16)b.x; o0[5]=(_Float16)b.y; o0[6]=(_Float16)b.z; o0[7]=(_Float16)b.w;
    o1[0]=(_Float16)c.x; o1[1]=(_Float16)c.y; o1[2]=(_Float16)c.z; o1[3]=(_Float16)c.w;
    o1[4]=(_Float16)d.x; o1[5]=(_Float16)d.y; o1[6]=(_Float16)d.z; o1[7]=(_Float16)d.w;
    h8* dp = (h8*)(eap + (size_t)i * EDIM);
    dp[0] = o0; dp[1] = o1;
}

// ---------------- GRU weight pre-pack ----------------
__global__ void k_packw(const float* __restrict__ Wih, const float* __restrict__ Whh,
                        uint2* __restrict__ gWa, u32* __restrict__ gWb) {
    int t = blockIdx.x * blockDim.x + threadIdx.x;
    if (t < 64 * 64) {
        int k = t >> 6, c = t & 63;
        gWa[t] = make_uint2(pack2(Wih[c * 64 + k], Wih[(64 + c) * 64 + k]),
                            pack2(Wih[(128 + c) * 64 + k], Whh[c * 64 + k]));
        gWb[t] = pack2(Whh[(64 + c) * 64 + k], Whh[(128 + c) * 64 + k]);
    }
}

// ---------------- LSTM weight transpose (coalesced reads in k_s2s) ----------------
__global__ void k_packl(const float* __restrict__ lWih, const float* __restrict__ lWhh,
                        float* __restrict__ WT1, float* __restrict__ WT2) {
    int t = blockIdx.x * blockDim.x + threadIdx.x;
    if (t < 256 * 128) { int g = t >> 7, k = t & 127; WT1[k * 256 + g] = lWih[g * 128 + k]; }
    if (t < 256 * 64)  { int g = t >> 6, k = t & 63;  WT2[k * 256 + g] = lWhh[g * 64 + k]; }
}

// ---------------- node embedding ----------------
__global__ void k_embed(const float* __restrict__ xf, const float* __restrict__ We,
                        const float* __restrict__ be, float* __restrict__ xh, int N) {
    __shared__ float Wl[NDIM * HID];
    for (int t = threadIdx.x; t < NDIM * HID; t += blockDim.x) Wl[t] = We[t];
    __syncthreads();
    int total = N * HID;
    int stride = gridDim.x * blockDim.x;
    for (int idx = blockIdx.x * blockDim.x + threadIdx.x; idx < total; idx += stride) {
        int n = idx >> 6, c = idx & 63;
        const float* xr = xf + n * NDIM;
        float acc = be[c];
#pragma unroll
        for (int k = 0; k < NDIM; k++) acc += xr[k] * Wl[k * HID + c];
        xh[idx] = acc;
    }
}

// ---------------- k_prep: Pd (-> Hb, f32) and Ps (f16) ----------------
__global__ void __launch_bounds__(256)
k_prep(const float* __restrict__ xh, const float* __restrict__ Wm1,
       const float* __restrict__ bm1, float* __restrict__ Hb,
       _Float16* __restrict__ PsH, int N) {
    __shared__ float Wl[64 * 256];
    for (int t = threadIdx.x; t < 64 * 256; t += 256) {
        int k = t >> 8, cc = t & 255;
        Wl[t] = (cc < 128) ? Wm1[k * 128 + cc] : Wm1[(64 + k) * 128 + (cc - 128)];
    }
    __syncthreads();
    int wv = threadIdx.x >> 6, lane = threadIdx.x & 63;
    int cc = lane * 4;
    float4 bias;
    if (lane < 32) bias = *(const float4*)&bm1[cc];
    else bias = make_float4(0.f, 0.f, 0.f, 0.f);
    int ngroups = (N + 7) >> 3;
    for (int g = blockIdx.x * 4 + wv; g < ngroups; g += gridDim.x * 4) {
        int base = rfl(g) * 8;
        const float* xp[8];
#pragma unroll
        for (int t = 0; t < 8; t++) {
            int d = base + t; if (d > N - 1) d = N - 1;
            xp[t] = xh + (size_t)d * 64;
        }
        float4 acc[8];
#pragma unroll
        for (int t = 0; t < 8; t++) acc[t] = bias;
#pragma unroll 2
        for (int k4 = 0; k4 < 16; k4++) {
            int k = k4 * 4;
            float4 xv4[8];
#pragma unroll
            for (int t = 0; t < 8; t++) xv4[t] = *(const float4*)&xp[t][k];
#pragma unroll
            for (int kk = 0; kk < 4; kk++) {
                float4 w = *(const float4*)&Wl[(k + kk) * 256 + cc];
#pragma unroll
                for (int t = 0; t < 8; t++) {
                    float xv = kk == 0 ? xv4[t].x : kk == 1 ? xv4[t].y : kk == 2 ? xv4[t].z : xv4[t].w;
                    acc[t].x += xv * w.x; acc[t].y += xv * w.y;
                    acc[t].z += xv * w.z; acc[t].w += xv * w.w;
                }
            }
        }
#pragma unroll
        for (int t = 0; t < 8; t++) {
            int d = base + t;
            if (d < N) {
                if (lane < 32) *(float4*)&Hb[(size_t)d * 128 + cc] = acc[t];
                else {
                    h4 o;
                    o[0] = (_Float16)acc[t].x; o[1] = (_Float16)acc[t].y;
                    o[2] = (_Float16)acc[t].z; o[3] = (_Float16)acc[t].w;
                    *(h4*)&PsH[(size_t)d * 128 + (cc - 128)] = o;
                }
            }
        }
    }
}

// ---------------- k_edge: fdot2 inner product ----------------
__global__ void __launch_bounds__(256)
k_edge(const _Float16* __restrict__ PsH, const _Float16* __restrict__ eap,
       const float* __restrict__ Wm1, const int* __restrict__ ptr,
       const int* __restrict__ slist, float* __restrict__ Hb, int N) {
    int c = threadIdx.x & 127;
    int half = threadIdx.x >> 7;
    h2 wh[8];
#pragma unroll
    for (int k = 0; k < 8; k++) {
        h2 t;
        t[0] = (_Float16)Wm1[128 * 128 + (2 * k) * 128 + c];
        t[1] = (_Float16)Wm1[128 * 128 + (2 * k + 1) * 128 + c];
        wh[k] = t;
    }
    for (int dd = blockIdx.x * 2 + half; dd < N; dd += gridDim.x * 2) {
        int d = rfl(dd);
        float pd = Hb[(size_t)d * 128 + c];
        int eb = rfl(ptr[d]), ee = rfl(ptr[d + 1]);
        const int* sp = slist + eb;
        const _Float16* ep = eap + (size_t)eb * EDIM;
        int ne = ee - eb;
        float acc = 0.f;
        int i = 0;
        for (; i + 8 <= ne; i += 8) {
            int ns[8];
#pragma unroll
            for (int j = 0; j < 8; j++) ns[j] = rfl(sp[i + j]);
            float pv[8];
#pragma unroll
            for (int j = 0; j < 8; j++) pv[j] = (float)PsH[(size_t)ns[j] * 128 + c];
#pragma unroll
            for (int j = 0; j < 8; j++) {
                union { uint4 u; h2 h[4]; } A, B;
                A.u = *(const uint4*)(ep + (size_t)(i + j) * EDIM);
                B.u = *(const uint4*)(ep + (size_t)(i + j) * EDIM + 8);
                float pe = 0.f;
#pragma unroll
                for (int k = 0; k < 4; k++) pe = __builtin_amdgcn_fdot2(A.h[k], wh[k], pe, false);
#pragma unroll
                for (int k = 0; k < 4; k++) pe = __builtin_amdgcn_fdot2(B.h[k], wh[4 + k], pe, false);
                acc += fmaxf(pd + pv[j] + pe, 0.f);
            }
        }
        for (; i < ne; i++) {
            int n0 = rfl(sp[i]);
            float pv = (float)PsH[(size_t)n0 * 128 + c];
            union { uint4 u; h2 h[4]; } A, B;
            A.u = *(const uint4*)(ep + (size_t)i * EDIM);
            B.u = *(const uint4*)(ep + (size_t)i * EDIM + 8);
            float pe = 0.f;
#pragma unroll
            for (int k = 0; k < 4; k++) pe = __builtin_amdgcn_fdot2(A.h[k], wh[k], pe, false);
#pragma unroll
            for (int k = 0; k < 4; k++) pe = __builtin_amdgcn_fdot2(B.h[k], wh[4 + k], pe, false);
            acc += fmaxf(pd + pv + pe, 0.f);
        }
        Hb[(size_t)d * 128 + c] = acc;
    }
}

// ---------------- m = H @ W_m2 + deg*b_m2 ----------------
__global__ void __launch_bounds__(256)
k_msg(const float* __restrict__ H, const float* __restrict__ Wm2,
      const float* __restrict__ bm2, const int* __restrict__ ptr,
      float* __restrict__ m, int N) {
    __shared__ float W2[128 * 64];
    for (int t = threadIdx.x; t < 128 * 64; t += 256) W2[t] = Wm2[t];
    __syncthreads();
    int wv = threadIdx.x >> 6, lane = threadIdx.x & 63;
    float b2 = bm2[lane];
    int ngroups = (N + 3) >> 2;
    for (int g = blockIdx.x * 4 + wv; g < ngroups; g += gridDim.x * 4) {
        int base = rfl(g) * 4;
        const float* hp[4];
#pragma unroll
        for (int t = 0; t < 4; t++) { int d = base + t; if (d > N - 1) d = N - 1; hp[t] = H + (size_t)d * 128; }
        float acc[4] = {0.f, 0.f, 0.f, 0.f};
#pragma unroll 2
        for (int k4 = 0; k4 < 32; k4++) {
            int k = k4 * 4;
            float4 h4v[4];
#pragma unroll
            for (int t = 0; t < 4; t++) h4v[t] = *(const float4*)&hp[t][k];
#pragma unroll
            for (int kk = 0; kk < 4; kk++) {
                float w = W2[(k + kk) * 64 + lane];
#pragma unroll
                for (int t = 0; t < 4; t++) {
                    float hv = kk == 0 ? h4v[t].x : kk == 1 ? h4v[t].y : kk == 2 ? h4v[t].z : h4v[t].w;
                    acc[t] += hv * w;
                }
            }
        }
#pragma unroll
        for (int t = 0; t < 4; t++) {
            int d = base + t;
            if (d < N) {
                float deg = (float)(ptr[d + 1] - ptr[d]);
                m[(size_t)d * 64 + lane] = acc[t] + deg * b2;
            }
        }
    }
}

// ---------------- GRU cell: wave-per-node, pre-packed bf16 weights ----------------
__global__ void __launch_bounds__(256)
k_gru(const float* __restrict__ m, const uint2* __restrict__ gWa,
      const u32* __restrict__ gWb, const float* __restrict__ bih,
      const float* __restrict__ bhh, float* __restrict__ xh, int N) {
    __shared__ uint2 Wa[64 * 64];
    __shared__ u32 Wb[64 * 64];
    {
        const uint4* s1 = (const uint4*)gWa;
        uint4* d1 = (uint4*)Wa;
        for (int t = threadIdx.x; t < 2048; t += 256) d1[t] = s1[t];
        const uint4* s2 = (const uint4*)gWb;
        uint4* d2 = (uint4*)Wb;
        for (int t = threadIdx.x; t < 1024; t += 256) d2[t] = s2[t];
    }
    __syncthreads();
    int wv = threadIdx.x >> 6, lane = threadIdx.x & 63;
    float br = bih[lane], bz = bih[64 + lane], bn = bih[128 + lane];
    float cr = bhh[lane], cz = bhh[64 + lane], cn = bhh[128 + lane];
    for (int dd = blockIdx.x * 4 + wv; dd < N; dd += gridDim.x * 4) {
        int d = rfl(dd);
        const float* mp = m + (size_t)d * 64;
        const float* hp = xh + (size_t)d * 64;
        float hv = hp[lane];
        float gir = br, giz = bz, gin = bn, ghr = cr, ghz = cz, ghn = cn;
#pragma unroll 2
        for (int k4 = 0; k4 < 16; k4++) {
            int k = k4 * 4;
            float4 m4 = *(const float4*)&mp[k];
            float4 h4v = *(const float4*)&hp[k];
#pragma unroll
            for (int kk = 0; kk < 4; kk++) {
                uint2 wa = Wa[(k + kk) * 64 + lane];
                u32 wb = Wb[(k + kk) * 64 + lane];
                float mk = kk == 0 ? m4.x : kk == 1 ? m4.y : kk == 2 ? m4.z : m4.w;
                float hk = kk == 0 ? h4v.x : kk == 1 ? h4v.y : kk == 2 ? h4v.z : h4v.w;
                gir += mk * blo(wa.x); giz += mk * bhi(wa.x); gin += mk * blo(wa.y);
                ghr += hk * bhi(wa.y); ghz += hk * blo(wb); ghn += hk * bhi(wb);
            }
        }
        float r = sigm(gir + ghr);
        float z = sigm(giz + ghz);
        float nn = tanhf(gin + r * ghn);
        xh[(size_t)d * 64 + lane] = (1.f - z) * nn + z * hv;
    }
}

// ---------------- fused Set2Set: transposed LSTM weights, split-K gates, online softmax ----------------
__global__ void __launch_bounds__(1024)
k_s2s(const float* __restrict__ xh, const int* __restrict__ gptr,
      const float* __restrict__ WT1, const float* __restrict__ WT2,
      const float* __restrict__ lbih, const float* __restrict__ lbhh,
      const float* __restrict__ Wr1, const float* __restrict__ br1,
      const float* __restrict__ Wr2, const float* __restrict__ br2,
      float* __restrict__ out) {
    int b = blockIdx.x, tid = threadIdx.x;
    __shared__ float xl[SCAP * 64];
    __shared__ float qs[128], qhl[64], qcs[64], g[256], red[16], asums[16], rvs[1024];
    int start = gptr[b], end = gptr[b + 1];
    int seg = end - start;
    bool uselds = (seg <= SCAP);
    if (uselds) {
        int tot = seg * 64;
        for (int t = tid; t < tot; t += 1024) xl[t] = xh[(size_t)start * 64 + t];
    }
    if (tid < 128) qs[tid] = 0.f;
    if (tid < 64) { qhl[tid] = 0.f; qcs[tid] = 0.f; }
    __syncthreads();
    int grp = tid >> 6, lane = tid & 63;
    int gate = tid & 255, part = tid >> 8;  // 4-way split-K
    for (int s = 0; s < 6; s++) {
        // LSTM gate pre-activations: partials over k-ranges, coalesced WT reads
        {
            float acc = 0.f;
            int k0 = part * 32;
#pragma unroll 8
            for (int k = k0; k < k0 + 32; k++) acc += qs[k] * WT1[k * 256 + gate];
            int k1 = part * 16;
#pragma unroll 8
            for (int k = k1; k < k1 + 16; k++) acc += qhl[k] * WT2[k * 256 + gate];
            rvs[tid] = acc;
        }
        __syncthreads();
        if (tid < 256) g[tid] = lbih[tid] + lbhh[tid] + rvs[tid] + rvs[256 + tid] + rvs[512 + tid] + rvs[768 + tid];
        __syncthreads();
        if (tid < 64) {
            float ig = sigm(g[tid]), fg = sigm(g[64 + tid]);
            float gg = tanhf(g[128 + tid]), og = sigm(g[192 + tid]);
            float c = fg * qcs[tid] + ig * gg;
            float h = og * tanhf(c);
            qcs[tid] = c; qhl[tid] = h; qs[tid] = h;
        }
        __syncthreads();
        // online-softmax attention (single pass)
        float qv = qhl[lane];
        float mloc = -3.4e38f, asl = 0.f, rv = 0.f;
        for (int n = grp; n < seg; n += 16) {
            float xv = uselds ? xl[n * 64 + lane] : xh[(size_t)(start + n) * 64 + lane];
            float p = xv * qv;
#pragma unroll
            for (int off = 32; off > 0; off >>= 1) p += __shfl_xor(p, off);
            float mnew = fmaxf(mloc, p);
            float corr = expf(mloc - mnew);
            float a = expf(p - mnew);
            asl = asl * corr + a;
            rv = rv * corr + a * xv;
            mloc = mnew;
        }
        if (lane == 0) red[grp] = mloc;
        __syncthreads();
        float gmax = red[0];
#pragma unroll
        for (int j = 1; j < 16; j++) gmax = fmaxf(gmax, red[j]);
        float sc = expf(mloc - gmax);
        rvs[tid] = rv * sc;
        if (lane == 0) asums[grp] = asl * sc;
        __syncthreads();
        if (tid < 64) {
            float rt = 0.f, at = 0.f;
#pragma unroll
            for (int j = 0; j < 16; j++) { rt += rvs[tid + 64 * j]; at += asums[j]; }
            qs[64 + tid] = (at > 0.f) ? rt / at : 0.f;
        }
        __syncthreads();
    }
    if (tid < 64) {
        float a2 = br1[tid];
#pragma unroll 8
        for (int k = 0; k < 128; k++) a2 += qs[k] * Wr1[k * 64 + tid];
        a2 = fmaxf(a2, 0.f);
        float v = a2 * Wr2[tid];
#pragma unroll
        for (int off = 32; off > 0; off >>= 1) v += __shfl_xor(v, off);
        if (tid == 0) out[b] = v + br2[0];
    }
}

extern "C" void kernel_launch(void* const* d_in, const int* in_sizes, int n_in,
                              void* d_out, int out_size, void* d_ws, size_t ws_size,
                              hipStream_t stream) {
    const float* x_feat = (const float*)d_in[0];
    const int*   ei     = (const int*)d_in[1];
    const float* eattr  = (const float*)d_in[2];
    const int*   batch  = (const int*)d_in[3];
    const float* W_emb  = (const float*)d_in[4];
    const float* b_emb  = (const float*)d_in[5];
    const float* W_m1   = (const float*)d_in[6];
    const float* b_m1   = (const float*)d_in[7];
    const float* W_m2   = (const float*)d_in[8];
    const float* b_m2   = (const float*)d_in[9];
    const float* gWih   = (const float*)d_in[10];
    const float* gWhh   = (const float*)d_in[11];
    const float* gbih   = (const float*)d_in[12];
    const float* gbhh   = (const float*)d_in[13];
    const float* lWih   = (const float*)d_in[14];
    const float* lWhh   = (const float*)d_in[15];
    const float* lbih   = (const float*)d_in[16];
    const float* lbhh   = (const float*)d_in[17];
    const float* Wr1    = (const float*)d_in[18];
    const float* br1    = (const float*)d_in[19];
    const float* Wr2    = (const float*)d_in[20];
    const float* br2    = (const float*)d_in[21];

    int N = in_sizes[0] / NDIM;   // 50000
    int E = in_sizes[1] / 2;      // 800000

    char* w = (char*)d_ws;
    auto alloc = [&](size_t b) { char* p = w; w += (b + 511) & ~(size_t)511; return p; };
    float*     xh    = (float*)alloc((size_t)N * 64 * 4);
    _Float16*  PsH   = (_Float16*)alloc((size_t)N * 128 * 2);
    float*     Hb    = (float*)alloc((size_t)N * 128 * 4);
    int*       ptr   = (int*)alloc((size_t)(N + 1) * 4);
    int*       slist = (int*)alloc((size_t)E * 4);
    _Float16*  eap   = (_Float16*)alloc((size_t)E * EDIM * 2);
    uint2*     gWa   = (uint2*)alloc((size_t)4096 * 8);
    u32*       gWb   = (u32*)alloc((size_t)4096 * 4);
    float*     WT1   = (float*)alloc((size_t)128 * 256 * 4);
    float*     WT2   = (float*)alloc((size_t)64 * 256 * 4);
    int*       gptr  = (int*)alloc((size_t)(NG + 1) * 4);
    int*       bsum  = (int*)alloc(128 * 4);
    int*       boff  = (int*)alloc(128 * 4);
    char* z0 = w;
    int*       cnt    = (int*)alloc((size_t)N * 4);
    int*       cursor = (int*)alloc((size_t)N * 4);
    char* z0e = w;
    // mb aliases eidx: eidx dead after k_permea, mb first written in k_msg
    char*      mbase = alloc((size_t)N * 64 * 4);
    float*     mb    = (float*)mbase;
    int*       eidx  = (int*)mbase;

    hipMemsetAsync(z0, 0, (size_t)(z0e - z0), stream);

    int NB = (N + 1023) / 1024;
    k_hist<<<1024, 256, 0, stream>>>(ei + E, E, cnt);
    k_scanA<<<NB, 1024, 0, stream>>>(cnt, ptr, bsum, N);
    k_scanB<<<1, 64, 0, stream>>>(bsum, boff, NB);
    k_scanC<<<(N + 256) / 256, 256, 0, stream>>>(ptr, boff, N, NB);
    k_gptr<<<3, 256, 0, stream>>>(batch, N, gptr);
    k_scatter<<<3125, 256, 0, stream>>>(ei, ei + E, E, ptr, cursor, eidx, slist);
    k_permea<<<(E + 255) / 256, 256, 0, stream>>>(eidx, eattr, eap, E);
    k_packw<<<16, 256, 0, stream>>>(gWih, gWhh, gWa, gWb);
    k_packl<<<128, 256, 0, stream>>>(lWih, lWhh, WT1, WT2);

    k_embed<<<2048, 256, 0, stream>>>(x_feat, W_emb, b_emb, xh, N);

    for (int r = 0; r < 3; r++) {
        k_prep<<<391, 256, 0, stream>>>(xh, W_m1, b_m1, Hb, PsH, N);
        k_edge<<<4096, 256, 0, stream>>>(PsH, eap, W_m1, ptr, slist, Hb, N);
        k_msg<<<1024, 256, 0, stream>>>(Hb, W_m2, b_m2, ptr, mb, N);
        k_gru<<<1280, 256, 0, stream>>>(mb, gWa, gWb, gbih, gbhh, xh, N);
    }
    k_s2s<<<NG, 1024, 0, stream>>>(xh, gptr, WT1, WT2, lbih, lbhh,
                                   Wr1, br1, Wr2, br2, (float*)d_out);
}